// Round 6
// baseline (547.678 us; speedup 1.0000x reference)
//
#include <hip/hip_runtime.h>
#include <hip/hip_bf16.h>

#define NN 100000
#define NE 1600000
#define FF 128
#define HH 128
#define CC 10
#define GG 64
#define NRANGE 8
#define RSPAN (NN / NRANGE)   // 12500

typedef __attribute__((ext_vector_type(8))) short short8;
typedef __attribute__((ext_vector_type(8))) unsigned short ushort8;
typedef __attribute__((ext_vector_type(4))) float f32x4;

__device__ inline float bf2f(unsigned short u) {
    union { unsigned int i; float f; } x;
    x.i = ((unsigned int)u) << 16;
    return x.f;
}
__device__ inline unsigned short f2bf(float f) {
    union { float f; unsigned int i; } x;
    x.f = f;
    unsigned int r = x.i + 0x7FFF + ((x.i >> 16) & 1);  // RNE
    return (unsigned short)(r >> 16);
}

// ---------------- f32 -> bf16 bulk convert (8 elems/thread) ----------------
__global__ __launch_bounds__(256) void f2bf_kernel(const float* __restrict__ x,
                                                   unsigned short* __restrict__ xb) {
    int i = blockIdx.x * blockDim.x + threadIdx.x;
    if (i >= NN * HH / 8) return;
    float4 v0 = ((const float4*)x)[i * 2];
    float4 v1 = ((const float4*)x)[i * 2 + 1];
    ushort8 o;
    o[0] = f2bf(v0.x); o[1] = f2bf(v0.y); o[2] = f2bf(v0.z); o[3] = f2bf(v0.w);
    o[4] = f2bf(v1.x); o[5] = f2bf(v1.y); o[6] = f2bf(v1.z); o[7] = f2bf(v1.w);
    ((ushort8*)xb)[i] = o;
}

// ---------------- weight combine + pack into MFMA B-fragment order (bf16) ----
__global__ void combw_kernel(const float* __restrict__ W1, const float* __restrict__ b1,
                             const float* __restrict__ Wr1, const float* __restrict__ br1,
                             const float* __restrict__ W2, const float* __restrict__ b2,
                             const float* __restrict__ Wr, const float* __restrict__ br,
                             unsigned short* __restrict__ Wpack, float* __restrict__ bc) {
    int idx = blockIdx.x * blockDim.x + threadIdx.x;
    if (idx >= 3 * 16384) return;
    int l = idx / 16384, rem = idx % 16384;
    int cb = rem / 2048;
    int kb = (rem / 512) % 4;
    int lane = (rem / 8) % 64;
    int j = rem % 8;
    int k = kb * 32 + (lane >> 4) * 8 + j;
    int c = cb * 16 + (lane & 15);
    int wi = k * HH + c;
    float v = (l == 0) ? 0.95f * W1[wi] + 0.05f * Wr1[wi]
                       : 0.95f * W2[(l - 1) * 16384 + wi] + 0.05f * Wr[wi];
    Wpack[idx] = f2bf(v);
    if (rem < HH) {
        bc[l * HH + rem] = (l == 0) ? 0.95f * b1[rem] + 0.05f * br1[rem]
                                    : 0.95f * b2[(l - 1) * HH + rem] + 0.05f * br[rem];
    }
}

// ------------- degree histogram over dst, dst-range binned + nt stream -------------
__global__ void hist_kernel(const int* __restrict__ ei, int* __restrict__ cnt) {
    int range = blockIdx.x & (NRANGE - 1);
    int lo = range * RSPAN, hi = lo + RSPAN;
    int tid = (blockIdx.x >> 3) * blockDim.x + threadIdx.x;
    int stride = (gridDim.x >> 3) * blockDim.x;
    for (int e = tid; e < NE; e += stride) {
        int d = __builtin_nontemporal_load(ei + NE + e);
        if (d >= lo && d < hi) atomicAdd(&cnt[d], 1);
    }
}

__global__ void deg_kernel(const int* __restrict__ cnt, float* __restrict__ dinv,
                           float* __restrict__ selfn) {
    int stride = gridDim.x * blockDim.x;
    for (int n = blockIdx.x * blockDim.x + threadIdx.x; n < NN; n += stride) {
        float dg = (float)cnt[n] + 1.0f;
        dinv[n] = rsqrtf(dg);
        selfn[n] = 1.0f / dg;
    }
}

// ---------------- 3-kernel exclusive scan of cnt -> offs ----------------
__global__ __launch_bounds__(256) void scan1_kernel(const int* __restrict__ cnt, int* __restrict__ bsum) {
    __shared__ int sh[256];
    int b = blockIdx.x, t = threadIdx.x;
    int base = b * 1024 + t * 4;
    int s = 0;
#pragma unroll
    for (int j = 0; j < 4; ++j) { int i = base + j; if (i < NN) s += cnt[i]; }
    sh[t] = s; __syncthreads();
    for (int off = 128; off; off >>= 1) { if (t < off) sh[t] += sh[t + off]; __syncthreads(); }
    if (t == 0) bsum[b] = sh[0];
}

__global__ void scan2_kernel(int* __restrict__ bsum, int nb) {
    if (threadIdx.x == 0 && blockIdx.x == 0) {
        int run = 0;
        for (int i = 0; i < nb; ++i) { int v = bsum[i]; bsum[i] = run; run += v; }
    }
}

__global__ __launch_bounds__(256) void scan3_kernel(const int* __restrict__ cnt, const int* __restrict__ bsum,
                                                    int* __restrict__ offs, int* __restrict__ cursor) {
    __shared__ int sh[256];
    int b = blockIdx.x, t = threadIdx.x;
    int base = b * 1024 + t * 4;
    int v[4]; int s = 0;
#pragma unroll
    for (int j = 0; j < 4; ++j) { int i = base + j; v[j] = (i < NN) ? cnt[i] : 0; s += v[j]; }
    sh[t] = s; __syncthreads();
    for (int off = 1; off < 256; off <<= 1) {
        int x = (t >= off) ? sh[t - off] : 0; __syncthreads();
        sh[t] += x; __syncthreads();
    }
    int excl = sh[t] - s + bsum[b];
#pragma unroll
    for (int j = 0; j < 4; ++j) {
        int i = base + j;
        if (i < NN) { offs[i] = excl; cursor[i] = excl; excl += v[j]; }
    }
    if (b == 0 && t == 0) offs[NN] = NE;
}

// ------------- CSR fill (src + enorm), dst-range binned + nt stream -------------
__global__ void csrfill_kernel(const int* __restrict__ ei, const float* __restrict__ dinv,
                               int* __restrict__ cursor, int* __restrict__ csrc,
                               float* __restrict__ cw) {
    int range = blockIdx.x & (NRANGE - 1);
    int lo = range * RSPAN, hi = lo + RSPAN;
    int tid = (blockIdx.x >> 3) * blockDim.x + threadIdx.x;
    int stride = (gridDim.x >> 3) * blockDim.x;
    for (int e = tid; e < NE; e += stride) {
        int d = __builtin_nontemporal_load(ei + NE + e);
        if (d >= lo && d < hi) {
            int s = __builtin_nontemporal_load(ei + e);
            int p = atomicAdd(&cursor[d], 1);
            csrc[p] = s;
            cw[p] = dinv[s] * dinv[d];
        }
    }
}

// ---------------- MFMA GEMM: out[N,128](bf16) = A[N,128](bf16) @ Wc ----------------
__global__ __launch_bounds__(256) void gemm_mfma_kernel(const unsigned short* __restrict__ A,
                                                        const unsigned short* __restrict__ Wp,
                                                        unsigned short* __restrict__ out,
                                                        int nrows) {
    int w = threadIdx.x >> 6;
    int l = threadIdx.x & 63;
    int m0 = blockIdx.x * 64 + w * 16;
    int kg = l >> 4;            // 0..3
    int cl = l & 15;            // A row / C col within 16-group
    int arow = m0 + cl;

    short8 a[4];
    if (arow < nrows) {
        const short8* Ar = (const short8*)(A + (size_t)arow * HH);
#pragma unroll
        for (int kb = 0; kb < 4; ++kb) a[kb] = Ar[kb * 4 + kg];
    } else {
        short8 z = {};
#pragma unroll
        for (int kb = 0; kb < 4; ++kb) a[kb] = z;
    }

#pragma unroll
    for (int cb = 0; cb < 8; ++cb) {
        f32x4 acc = {0.f, 0.f, 0.f, 0.f};
#pragma unroll
        for (int kb = 0; kb < 4; ++kb) {
            short8 b = *(const short8*)(Wp + (size_t)(cb * 4 + kb) * 512 + l * 8);
            acc = __builtin_amdgcn_mfma_f32_16x16x32_bf16(a[kb], b, acc, 0, 0, 0);
        }
#pragma unroll
        for (int r = 0; r < 4; ++r) {
            int orow = m0 + kg * 4 + r;
            if (orow < nrows) out[(size_t)orow * HH + cb * 16 + cl] = f2bf(acc[r]);
        }
    }
}

// ---------- aggregation + self + bias + relu (bf16 rows, 16 lanes/node) ----------
__global__ __launch_bounds__(256) void agg_relu_kernel(const unsigned short* __restrict__ hT,
                                                       const int* __restrict__ offs,
                                                       const int* __restrict__ csrc,
                                                       const float* __restrict__ cw,
                                                       const float* __restrict__ selfn,
                                                       const float* __restrict__ bias,
                                                       unsigned short* __restrict__ hOut) {
    int n = blockIdx.x * 16 + (threadIdx.x >> 4);
    if (n >= NN) return;
    int lane = threadIdx.x & 15;          // features lane*8 .. lane*8+7
    int beg = offs[n], end = offs[n + 1];
    const ushort8* h8 = (const ushort8*)hT;
    float acc[8] = {};
    int e = beg;
    for (; e + 3 < end; e += 4) {
        int s0 = csrc[e], s1 = csrc[e + 1], s2 = csrc[e + 2], s3 = csrc[e + 3];
        float w0 = cw[e], w1 = cw[e + 1], w2 = cw[e + 2], w3 = cw[e + 3];
        ushort8 v0 = h8[(size_t)s0 * 16 + lane];
        ushort8 v1 = h8[(size_t)s1 * 16 + lane];
        ushort8 v2 = h8[(size_t)s2 * 16 + lane];
        ushort8 v3 = h8[(size_t)s3 * 16 + lane];
#pragma unroll
        for (int j = 0; j < 8; ++j) {
            acc[j] = fmaf(bf2f(v0[j]), w0, acc[j]);
            acc[j] = fmaf(bf2f(v1[j]), w1, acc[j]);
            acc[j] = fmaf(bf2f(v2[j]), w2, acc[j]);
            acc[j] = fmaf(bf2f(v3[j]), w3, acc[j]);
        }
    }
    for (; e < end; ++e) {
        int s = csrc[e];
        float w = cw[e];
        ushort8 v = h8[(size_t)s * 16 + lane];
#pragma unroll
        for (int j = 0; j < 8; ++j) acc[j] = fmaf(bf2f(v[j]), w, acc[j]);
    }
    float sn = selfn[n];
    ushort8 hv = h8[(size_t)n * 16 + lane];
    float4 bv0 = ((const float4*)bias)[lane * 2];
    float4 bv1 = ((const float4*)bias)[lane * 2 + 1];
    float bb[8] = {bv0.x, bv0.y, bv0.z, bv0.w, bv1.x, bv1.y, bv1.z, bv1.w};
    ushort8 o;
#pragma unroll
    for (int j = 0; j < 8; ++j) {
        float v = fmaxf(acc[j] + bf2f(hv[j]) * sn + bb[j], 0.f);
        o[j] = f2bf(v);
    }
    ((ushort8*)hOut)[(size_t)n * 16 + lane] = o;
}

// ---------------- pooling: counts via binary search (batch is sorted) ----------------
__global__ void poolcnt_bs_kernel(const int* __restrict__ batch, int* __restrict__ pcnt) {
    int g = threadIdx.x;
    if (g >= GG) return;
    int lo = 0, hi = NN;
    while (lo < hi) { int mid = (lo + hi) >> 1; if (batch[mid] < g) lo = mid + 1; else hi = mid; }
    int lb = lo;
    lo = 0; hi = NN;
    while (lo < hi) { int mid = (lo + hi) >> 1; if (batch[mid] <= g) lo = mid + 1; else hi = mid; }
    pcnt[g] = lo - lb;
}

__global__ __launch_bounds__(128) void poolsum_kernel(const unsigned short* __restrict__ h,
                                                      const int* __restrict__ batch,
                                                      float* __restrict__ psum) {
    const int CH = 256;
    int start = blockIdx.x * CH;
    if (start >= NN) return;
    int endn = min(start + CH, NN);
    int t = threadIdx.x;
    int curg = batch[start];
    float acc = 0.f;
    for (int n = start; n < endn; ++n) {
        int g = batch[n];
        if (g != curg) { atomicAdd(&psum[curg * HH + t], acc); acc = 0.f; curg = g; }
        acc += bf2f(h[(size_t)n * HH + t]);
    }
    atomicAdd(&psum[curg * HH + t], acc);
}

// ---------------- readout MLP + log_softmax ----------------
__global__ __launch_bounds__(128) void mlp_kernel(const float* __restrict__ psum,
                                                  const int* __restrict__ pcnt,
                                                  const float* __restrict__ Wl1,
                                                  const float* __restrict__ bl1,
                                                  const float* __restrict__ Wl2,
                                                  const float* __restrict__ bl2,
                                                  float* __restrict__ out) {
    __shared__ float p[128], o1[128], lg[CC];
    int g = blockIdx.x, t = threadIdx.x;
    float cnt = fmaxf((float)pcnt[g], 1.0f);
    p[t] = psum[g * HH + t] / cnt;
    __syncthreads();
    float acc = bl1[t];
    for (int k = 0; k < HH; ++k) acc = fmaf(p[k], Wl1[k * HH + t], acc);
    o1[t] = fmaxf(acc, 0.f);
    __syncthreads();
    if (t < CC) {
        float a2 = bl2[t];
        for (int j = 0; j < HH; ++j) a2 = fmaf(o1[j], Wl2[j * CC + t], a2);
        lg[t] = a2;
    }
    __syncthreads();
    if (t == 0) {
        float m = lg[0];
        for (int c = 1; c < CC; ++c) m = fmaxf(m, lg[c]);
        float s = 0.f;
        for (int c = 0; c < CC; ++c) s += expf(lg[c] - m);
        float ls = logf(s);
        for (int c = 0; c < CC; ++c) out[g * CC + c] = lg[c] - m - ls;
    }
}

extern "C" void kernel_launch(void* const* d_in, const int* in_sizes, int n_in,
                              void* d_out, int out_size, void* d_ws, size_t ws_size,
                              hipStream_t stream) {
    const float* x   = (const float*)d_in[0];
    const int*   ei  = (const int*)d_in[1];
    const int*   bat = (const int*)d_in[2];
    const float* W1  = (const float*)d_in[3];
    const float* b1  = (const float*)d_in[4];
    const float* Wr1 = (const float*)d_in[5];
    const float* br1 = (const float*)d_in[6];
    const float* W2  = (const float*)d_in[7];
    const float* b2  = (const float*)d_in[8];
    const float* Wr  = (const float*)d_in[9];
    const float* br  = (const float*)d_in[10];
    const float* Wl1 = (const float*)d_in[11];
    const float* bl1 = (const float*)d_in[12];
    const float* Wl2 = (const float*)d_in[13];
    const float* bl2 = (const float*)d_in[14];
    float* out = (float*)d_out;

    // workspace carve-up (256B aligned)
    char* base = (char*)d_ws;
    size_t off = 0;
    auto alloc = [&](size_t bytes) {
        void* p = base + off;
        off += (bytes + 255) & ~(size_t)255;
        return p;
    };
    unsigned short* xb   = (unsigned short*)alloc((size_t)NN * HH * 2);
    unsigned short* bufT = (unsigned short*)alloc((size_t)NN * HH * 2);
    unsigned short* bufH = (unsigned short*)alloc((size_t)NN * HH * 2);
    int*   csrc   = (int*)alloc((size_t)NE * 4);
    float* cw     = (float*)alloc((size_t)NE * 4);
    int*   offs   = (int*)alloc((size_t)(NN + 1) * 4);
    int*   cursor = (int*)alloc((size_t)NN * 4);
    int*   cnt    = (int*)alloc((size_t)NN * 4);
    float* dinv   = (float*)alloc((size_t)NN * 4);
    float* selfn  = (float*)alloc((size_t)NN * 4);
    int*   bsum   = (int*)alloc(128 * 4);
    unsigned short* Wpack = (unsigned short*)alloc(3 * 16384 * 2);
    float* bc     = (float*)alloc(3 * HH * 4);
    float* psum   = (float*)alloc(GG * HH * 4);
    int*   pcnt   = (int*)alloc(GG * 4);
    (void)ws_size; (void)in_sizes; (void)n_in; (void)out_size;

    hipMemsetAsync(cnt, 0, (size_t)NN * 4, stream);
    hipMemsetAsync(psum, 0, (size_t)GG * HH * 4, stream);

    // input convert + combined packed weights
    f2bf_kernel<<<(NN * HH / 8 + 255) / 256, 256, 0, stream>>>(x, xb);
    combw_kernel<<<(3 * 16384 + 255) / 256, 256, 0, stream>>>(W1, b1, Wr1, br1, W2, b2, Wr, br, Wpack, bc);

    // graph preprocessing (hist/csrfill are dst-range binned; ei stream is non-temporal)
    hist_kernel<<<8 * 256, 256, 0, stream>>>(ei, cnt);
    deg_kernel<<<512, 256, 0, stream>>>(cnt, dinv, selfn);
    const int NB = (NN + 1023) / 1024;  // 98
    scan1_kernel<<<NB, 256, 0, stream>>>(cnt, bsum);
    scan2_kernel<<<1, 64, 0, stream>>>(bsum, NB);
    scan3_kernel<<<NB, 256, 0, stream>>>(cnt, bsum, offs, cursor);
    csrfill_kernel<<<8 * 256, 256, 0, stream>>>(ei, dinv, cursor, csrc, cw);

    const int GEMM_BLOCKS = (NN + 63) / 64;
    const int AGG_BLOCKS = (NN + 15) / 16;
    // layer 0
    gemm_mfma_kernel<<<GEMM_BLOCKS, 256, 0, stream>>>(xb, Wpack, bufT, NN);
    agg_relu_kernel<<<AGG_BLOCKS, 256, 0, stream>>>(bufT, offs, csrc, cw, selfn, bc, bufH);
    // layer 1
    gemm_mfma_kernel<<<GEMM_BLOCKS, 256, 0, stream>>>(bufH, Wpack + 16384, bufT, NN);
    agg_relu_kernel<<<AGG_BLOCKS, 256, 0, stream>>>(bufT, offs, csrc, cw, selfn, bc + HH, bufH);
    // layer 2
    gemm_mfma_kernel<<<GEMM_BLOCKS, 256, 0, stream>>>(bufH, Wpack + 2 * 16384, bufT, NN);
    agg_relu_kernel<<<AGG_BLOCKS, 256, 0, stream>>>(bufT, offs, csrc, cw, selfn, bc + 2 * HH, bufH);

    // pooling + readout
    poolcnt_bs_kernel<<<1, 64, 0, stream>>>(bat, pcnt);
    poolsum_kernel<<<(NN + 255) / 256, 128, 0, stream>>>(bufH, bat, psum);
    mlp_kernel<<<GG, 128, 0, stream>>>(psum, pcnt, Wl1, bl1, Wl2, bl2, out);
}

// Round 7
// 456.291 us; speedup vs baseline: 1.2003x; 1.2003x over previous
//
#include <hip/hip_runtime.h>
#include <hip/hip_bf16.h>

#define NN 100000
#define NE 1600000
#define FF 128
#define HH 128
#define CC 10
#define GG 64

#define NCHUNK 2048
#define CE 782            // ceil(NE/NCHUNK)
#define NBUCKET 128
#define BSPAN 782         // ceil(NN/NBUCKET)

typedef __attribute__((ext_vector_type(8))) short short8;
typedef __attribute__((ext_vector_type(8))) unsigned short ushort8;
typedef __attribute__((ext_vector_type(4))) float f32x4;

__device__ inline float bf2f(unsigned short u) {
    union { unsigned int i; float f; } x;
    x.i = ((unsigned int)u) << 16;
    return x.f;
}
__device__ inline unsigned short f2bf(float f) {
    union { float f; unsigned int i; } x;
    x.f = f;
    unsigned int r = x.i + 0x7FFF + ((x.i >> 16) & 1);  // RNE
    return (unsigned short)(r >> 16);
}

// ---------------- f32 -> bf16 bulk convert ----------------
__global__ __launch_bounds__(256) void f2bf_kernel(const float* __restrict__ x,
                                                   unsigned short* __restrict__ xb) {
    int i = blockIdx.x * blockDim.x + threadIdx.x;
    if (i >= NN * HH / 8) return;
    float4 v0 = ((const float4*)x)[i * 2];
    float4 v1 = ((const float4*)x)[i * 2 + 1];
    ushort8 o;
    o[0] = f2bf(v0.x); o[1] = f2bf(v0.y); o[2] = f2bf(v0.z); o[3] = f2bf(v0.w);
    o[4] = f2bf(v1.x); o[5] = f2bf(v1.y); o[6] = f2bf(v1.z); o[7] = f2bf(v1.w);
    ((ushort8*)xb)[i] = o;
}

// ---------------- weight combine + pack into MFMA B-fragment order ----------------
__global__ void combw_kernel(const float* __restrict__ W1, const float* __restrict__ b1,
                             const float* __restrict__ Wr1, const float* __restrict__ br1,
                             const float* __restrict__ W2, const float* __restrict__ b2,
                             const float* __restrict__ Wr, const float* __restrict__ br,
                             unsigned short* __restrict__ Wpack, float* __restrict__ bc) {
    int idx = blockIdx.x * blockDim.x + threadIdx.x;
    if (idx >= 3 * 16384) return;
    int l = idx / 16384, rem = idx % 16384;
    int cb = rem / 2048;
    int kb = (rem / 512) % 4;
    int lane = (rem / 8) % 64;
    int j = rem % 8;
    int k = kb * 32 + (lane >> 4) * 8 + j;
    int c = cb * 16 + (lane & 15);
    int wi = k * HH + c;
    float v = (l == 0) ? 0.95f * W1[wi] + 0.05f * Wr1[wi]
                       : 0.95f * W2[(l - 1) * 16384 + wi] + 0.05f * Wr[wi];
    Wpack[idx] = f2bf(v);
    if (rem < HH) {
        bc[l * HH + rem] = (l == 0) ? 0.95f * b1[rem] + 0.05f * br1[rem]
                                    : 0.95f * b2[(l - 1) * HH + rem] + 0.05f * br[rem];
    }
}

// ============ Phase A: deterministic edge partition by dst bucket ============
// A1: per-chunk per-bucket counts (LDS histogram, no global atomics)
__global__ __launch_bounds__(256) void partA1_kernel(const int* __restrict__ ei,
                                                     int* __restrict__ cc) {
    __shared__ int h[NBUCKET];
    int c = blockIdx.x, t = threadIdx.x;
    if (t < NBUCKET) h[t] = 0;
    __syncthreads();
    int beg = c * CE, end = min(beg + CE, NE);
    for (int e = beg + t; e < end; e += 256) {
        int d = ei[NE + e];
        atomicAdd(&h[d / BSPAN], 1);
    }
    __syncthreads();
    if (t < NBUCKET) cc[c * NBUCKET + t] = h[t];
}

// A2: per-bucket exclusive scan over 2048 chunks (in-place on cc); tot[b] out
__global__ __launch_bounds__(256) void partA2_kernel(int* __restrict__ cc,
                                                     int* __restrict__ tot) {
    __shared__ int sh[256];
    int b = blockIdx.x, t = threadIdx.x;
    int v[8]; int s = 0;
#pragma unroll
    for (int i = 0; i < 8; ++i) { v[i] = cc[(t * 8 + i) * NBUCKET + b]; s += v[i]; }
    sh[t] = s; __syncthreads();
    for (int off = 1; off < 256; off <<= 1) {
        int x = (t >= off) ? sh[t - off] : 0; __syncthreads();
        sh[t] += x; __syncthreads();
    }
    int excl = sh[t] - s;
#pragma unroll
    for (int i = 0; i < 8; ++i) {
        cc[(t * 8 + i) * NBUCKET + b] = excl;
        excl += v[i];
    }
    if (t == 255) tot[b] = sh[255];
}

// scanB: bucket bases bb[NBUCKET+1]
__global__ void scanB_kernel(const int* __restrict__ tot, int* __restrict__ bb) {
    if (threadIdx.x == 0 && blockIdx.x == 0) {
        int run = 0;
        for (int b = 0; b < NBUCKET; ++b) { bb[b] = run; run += tot[b]; }
        bb[NBUCKET] = run;
    }
}

// A3: scatter edges into bucket-partitioned arrays via LDS cursors
__global__ __launch_bounds__(256) void partA3_kernel(const int* __restrict__ ei,
                                                     const int* __restrict__ cc,
                                                     const int* __restrict__ bb,
                                                     int* __restrict__ eb_dst,
                                                     int* __restrict__ eb_src) {
    __shared__ int cur[NBUCKET];
    int c = blockIdx.x, t = threadIdx.x;
    if (t < NBUCKET) cur[t] = bb[t] + cc[c * NBUCKET + t];
    __syncthreads();
    int beg = c * CE, end = min(beg + CE, NE);
    for (int e = beg + t; e < end; e += 256) {
        int d = ei[NE + e];
        int s = ei[e];
        int p = atomicAdd(&cur[d / BSPAN], 1);
        eb_dst[p] = d;
        eb_src[p] = s;
    }
}

// B1: per-bucket per-node degree counts (LDS histogram) -> cnt
__global__ __launch_bounds__(256) void partB1_kernel(const int* __restrict__ eb_dst,
                                                     const int* __restrict__ bb,
                                                     int* __restrict__ cnt) {
    __shared__ int h[BSPAN];
    int b = blockIdx.x, t = threadIdx.x;
    int lo = b * BSPAN;
    int span = min(BSPAN, NN - lo);
    if (span <= 0) return;
    for (int i = t; i < span; i += 256) h[i] = 0;
    __syncthreads();
    int beg = bb[b], end = bb[b + 1];
    for (int e = beg + t; e < end; e += 256)
        atomicAdd(&h[eb_dst[e] - lo], 1);
    __syncthreads();
    for (int i = t; i < span; i += 256) cnt[lo + i] = h[i];
}

__global__ void deg_kernel(const int* __restrict__ cnt, float* __restrict__ dinv,
                           float* __restrict__ selfn) {
    int stride = gridDim.x * blockDim.x;
    for (int n = blockIdx.x * blockDim.x + threadIdx.x; n < NN; n += stride) {
        float dg = (float)cnt[n] + 1.0f;
        dinv[n] = rsqrtf(dg);
        selfn[n] = 1.0f / dg;
    }
}

// ---------------- 3-kernel exclusive scan of cnt -> offs ----------------
__global__ __launch_bounds__(256) void scan1_kernel(const int* __restrict__ cnt, int* __restrict__ bsum) {
    __shared__ int sh[256];
    int b = blockIdx.x, t = threadIdx.x;
    int base = b * 1024 + t * 4;
    int s = 0;
#pragma unroll
    for (int j = 0; j < 4; ++j) { int i = base + j; if (i < NN) s += cnt[i]; }
    sh[t] = s; __syncthreads();
    for (int off = 128; off; off >>= 1) { if (t < off) sh[t] += sh[t + off]; __syncthreads(); }
    if (t == 0) bsum[b] = sh[0];
}

__global__ void scan2_kernel(int* __restrict__ bsum, int nb) {
    if (threadIdx.x == 0 && blockIdx.x == 0) {
        int run = 0;
        for (int i = 0; i < nb; ++i) { int v = bsum[i]; bsum[i] = run; run += v; }
    }
}

__global__ __launch_bounds__(256) void scan3_kernel(const int* __restrict__ cnt, const int* __restrict__ bsum,
                                                    int* __restrict__ offs) {
    __shared__ int sh[256];
    int b = blockIdx.x, t = threadIdx.x;
    int base = b * 1024 + t * 4;
    int v[4]; int s = 0;
#pragma unroll
    for (int j = 0; j < 4; ++j) { int i = base + j; v[j] = (i < NN) ? cnt[i] : 0; s += v[j]; }
    sh[t] = s; __syncthreads();
    for (int off = 1; off < 256; off <<= 1) {
        int x = (t >= off) ? sh[t - off] : 0; __syncthreads();
        sh[t] += x; __syncthreads();
    }
    int excl = sh[t] - s + bsum[b];
#pragma unroll
    for (int j = 0; j < 4; ++j) {
        int i = base + j;
        if (i < NN) { offs[i] = excl; excl += v[j]; }
    }
    if (b == 0 && t == 0) offs[NN] = NE;
}

// B2: final CSR fill from bucketed edges; LDS cursors + LDS dinv slice.
// Scatter target per block is a ~200KB contiguous L2-resident region.
__global__ __launch_bounds__(256) void partB2_kernel(const int* __restrict__ eb_dst,
                                                     const int* __restrict__ eb_src,
                                                     const int* __restrict__ bb,
                                                     const int* __restrict__ offs,
                                                     const float* __restrict__ dinv,
                                                     int* __restrict__ csrc,
                                                     float* __restrict__ cw) {
    __shared__ int lcur[BSPAN];
    __shared__ float ldinv[BSPAN];
    int b = blockIdx.x, t = threadIdx.x;
    int lo = b * BSPAN;
    int span = min(BSPAN, NN - lo);
    if (span <= 0) return;
    for (int i = t; i < span; i += 256) {
        lcur[i] = offs[lo + i];
        ldinv[i] = dinv[lo + i];
    }
    __syncthreads();
    int beg = bb[b], end = bb[b + 1];
    for (int e = beg + t; e < end; e += 256) {
        int d = eb_dst[e] - lo;
        int s = eb_src[e];
        int p = atomicAdd(&lcur[d], 1);
        csrc[p] = s;
        cw[p] = dinv[s] * ldinv[d];
    }
}

// ---------------- MFMA GEMM: out[N,128](bf16) = A[N,128](bf16) @ Wc ----------------
__global__ __launch_bounds__(256) void gemm_mfma_kernel(const unsigned short* __restrict__ A,
                                                        const unsigned short* __restrict__ Wp,
                                                        unsigned short* __restrict__ out,
                                                        int nrows) {
    int w = threadIdx.x >> 6;
    int l = threadIdx.x & 63;
    int m0 = blockIdx.x * 64 + w * 16;
    int kg = l >> 4;            // 0..3
    int cl = l & 15;            // A row / C col within 16-group
    int arow = m0 + cl;

    short8 a[4];
    if (arow < nrows) {
        const short8* Ar = (const short8*)(A + (size_t)arow * HH);
#pragma unroll
        for (int kb = 0; kb < 4; ++kb) a[kb] = Ar[kb * 4 + kg];
    } else {
        short8 z = {};
#pragma unroll
        for (int kb = 0; kb < 4; ++kb) a[kb] = z;
    }

#pragma unroll
    for (int cb = 0; cb < 8; ++cb) {
        f32x4 acc = {0.f, 0.f, 0.f, 0.f};
#pragma unroll
        for (int kb = 0; kb < 4; ++kb) {
            short8 b = *(const short8*)(Wp + (size_t)(cb * 4 + kb) * 512 + l * 8);
            acc = __builtin_amdgcn_mfma_f32_16x16x32_bf16(a[kb], b, acc, 0, 0, 0);
        }
#pragma unroll
        for (int r = 0; r < 4; ++r) {
            int orow = m0 + kg * 4 + r;
            if (orow < nrows) out[(size_t)orow * HH + cb * 16 + cl] = f2bf(acc[r]);
        }
    }
}

// ---------- aggregation + self + bias + relu (bf16 rows, 16 lanes/node) ----------
__global__ __launch_bounds__(256) void agg_relu_kernel(const unsigned short* __restrict__ hT,
                                                       const int* __restrict__ offs,
                                                       const int* __restrict__ csrc,
                                                       const float* __restrict__ cw,
                                                       const float* __restrict__ selfn,
                                                       const float* __restrict__ bias,
                                                       unsigned short* __restrict__ hOut) {
    int n = blockIdx.x * 16 + (threadIdx.x >> 4);
    if (n >= NN) return;
    int lane = threadIdx.x & 15;          // features lane*8 .. lane*8+7
    int beg = offs[n], end = offs[n + 1];
    const ushort8* h8 = (const ushort8*)hT;
    float acc[8] = {};
    int e = beg;
    for (; e + 3 < end; e += 4) {
        int s0 = csrc[e], s1 = csrc[e + 1], s2 = csrc[e + 2], s3 = csrc[e + 3];
        float w0 = cw[e], w1 = cw[e + 1], w2 = cw[e + 2], w3 = cw[e + 3];
        ushort8 v0 = h8[(size_t)s0 * 16 + lane];
        ushort8 v1 = h8[(size_t)s1 * 16 + lane];
        ushort8 v2 = h8[(size_t)s2 * 16 + lane];
        ushort8 v3 = h8[(size_t)s3 * 16 + lane];
#pragma unroll
        for (int j = 0; j < 8; ++j) {
            acc[j] = fmaf(bf2f(v0[j]), w0, acc[j]);
            acc[j] = fmaf(bf2f(v1[j]), w1, acc[j]);
            acc[j] = fmaf(bf2f(v2[j]), w2, acc[j]);
            acc[j] = fmaf(bf2f(v3[j]), w3, acc[j]);
        }
    }
    for (; e < end; ++e) {
        int s = csrc[e];
        float w = cw[e];
        ushort8 v = h8[(size_t)s * 16 + lane];
#pragma unroll
        for (int j = 0; j < 8; ++j) acc[j] = fmaf(bf2f(v[j]), w, acc[j]);
    }
    float sn = selfn[n];
    ushort8 hv = h8[(size_t)n * 16 + lane];
    float4 bv0 = ((const float4*)bias)[lane * 2];
    float4 bv1 = ((const float4*)bias)[lane * 2 + 1];
    float bb[8] = {bv0.x, bv0.y, bv0.z, bv0.w, bv1.x, bv1.y, bv1.z, bv1.w};
    ushort8 o;
#pragma unroll
    for (int j = 0; j < 8; ++j) {
        float v = fmaxf(acc[j] + bf2f(hv[j]) * sn + bb[j], 0.f);
        o[j] = f2bf(v);
    }
    ((ushort8*)hOut)[(size_t)n * 16 + lane] = o;
}

// ---------------- pooling: counts via binary search (batch is sorted) ----------------
__global__ void poolcnt_bs_kernel(const int* __restrict__ batch, int* __restrict__ pcnt) {
    int g = threadIdx.x;
    if (g >= GG) return;
    int lo = 0, hi = NN;
    while (lo < hi) { int mid = (lo + hi) >> 1; if (batch[mid] < g) lo = mid + 1; else hi = mid; }
    int lb = lo;
    lo = 0; hi = NN;
    while (lo < hi) { int mid = (lo + hi) >> 1; if (batch[mid] <= g) lo = mid + 1; else hi = mid; }
    pcnt[g] = lo - lb;
}

__global__ __launch_bounds__(128) void poolsum_kernel(const unsigned short* __restrict__ h,
                                                      const int* __restrict__ batch,
                                                      float* __restrict__ psum) {
    const int CH = 256;
    int start = blockIdx.x * CH;
    if (start >= NN) return;
    int endn = min(start + CH, NN);
    int t = threadIdx.x;
    int curg = batch[start];
    float acc = 0.f;
    for (int n = start; n < endn; ++n) {
        int g = batch[n];
        if (g != curg) { atomicAdd(&psum[curg * HH + t], acc); acc = 0.f; curg = g; }
        acc += bf2f(h[(size_t)n * HH + t]);
    }
    atomicAdd(&psum[curg * HH + t], acc);
}

// ---------------- readout MLP + log_softmax ----------------
__global__ __launch_bounds__(128) void mlp_kernel(const float* __restrict__ psum,
                                                  const int* __restrict__ pcnt,
                                                  const float* __restrict__ Wl1,
                                                  const float* __restrict__ bl1,
                                                  const float* __restrict__ Wl2,
                                                  const float* __restrict__ bl2,
                                                  float* __restrict__ out) {
    __shared__ float p[128], o1[128], lg[CC];
    int g = blockIdx.x, t = threadIdx.x;
    float cnt = fmaxf((float)pcnt[g], 1.0f);
    p[t] = psum[g * HH + t] / cnt;
    __syncthreads();
    float acc = bl1[t];
    for (int k = 0; k < HH; ++k) acc = fmaf(p[k], Wl1[k * HH + t], acc);
    o1[t] = fmaxf(acc, 0.f);
    __syncthreads();
    if (t < CC) {
        float a2 = bl2[t];
        for (int j = 0; j < HH; ++j) a2 = fmaf(o1[j], Wl2[j * CC + t], a2);
        lg[t] = a2;
    }
    __syncthreads();
    if (t == 0) {
        float m = lg[0];
        for (int c = 1; c < CC; ++c) m = fmaxf(m, lg[c]);
        float s = 0.f;
        for (int c = 0; c < CC; ++c) s += expf(lg[c] - m);
        float ls = logf(s);
        for (int c = 0; c < CC; ++c) out[g * CC + c] = lg[c] - m - ls;
    }
}

extern "C" void kernel_launch(void* const* d_in, const int* in_sizes, int n_in,
                              void* d_out, int out_size, void* d_ws, size_t ws_size,
                              hipStream_t stream) {
    const float* x   = (const float*)d_in[0];
    const int*   ei  = (const int*)d_in[1];
    const int*   bat = (const int*)d_in[2];
    const float* W1  = (const float*)d_in[3];
    const float* b1  = (const float*)d_in[4];
    const float* Wr1 = (const float*)d_in[5];
    const float* br1 = (const float*)d_in[6];
    const float* W2  = (const float*)d_in[7];
    const float* b2  = (const float*)d_in[8];
    const float* Wr  = (const float*)d_in[9];
    const float* br  = (const float*)d_in[10];
    const float* Wl1 = (const float*)d_in[11];
    const float* bl1 = (const float*)d_in[12];
    const float* Wl2 = (const float*)d_in[13];
    const float* bl2 = (const float*)d_in[14];
    float* out = (float*)d_out;

    // workspace carve-up (256B aligned)
    char* base = (char*)d_ws;
    size_t off = 0;
    auto alloc = [&](size_t bytes) {
        void* p = base + off;
        off += (bytes + 255) & ~(size_t)255;
        return p;
    };
    unsigned short* xb   = (unsigned short*)alloc((size_t)NN * HH * 2);
    unsigned short* bufT = (unsigned short*)alloc((size_t)NN * HH * 2);
    unsigned short* bufH = (unsigned short*)alloc((size_t)NN * HH * 2);
    int*   csrc   = (int*)alloc((size_t)NE * 4);
    float* cw     = (float*)alloc((size_t)NE * 4);
    int*   offs   = (int*)alloc((size_t)(NN + 1) * 4);
    int*   cnt    = (int*)alloc((size_t)NN * 4);
    float* dinv   = (float*)alloc((size_t)NN * 4);
    float* selfn  = (float*)alloc((size_t)NN * 4);
    int*   bsum   = (int*)alloc(128 * 4);
    unsigned short* Wpack = (unsigned short*)alloc(3 * 16384 * 2);
    float* bc     = (float*)alloc(3 * HH * 4);
    float* psum   = (float*)alloc(GG * HH * 4);
    int*   pcnt   = (int*)alloc(GG * 4);
    int*   tot    = (int*)alloc(NBUCKET * 4);
    int*   bb     = (int*)alloc((NBUCKET + 1) * 4);
    // aliases: partition scratch lives in bufT/bufH (dead until gemm/agg)
    int* eb_dst = (int*)bufT;                 // NE ints = 6.4MB
    int* eb_src = (int*)bufT + NE;            // NE ints = 6.4MB (bufT holds 25.6MB)
    int* cc     = (int*)bufH;                 // NCHUNK*NBUCKET ints = 1MB
    (void)ws_size; (void)in_sizes; (void)n_in; (void)out_size;

    hipMemsetAsync(psum, 0, (size_t)GG * HH * 4, stream);

    // input convert + combined packed weights
    f2bf_kernel<<<(NN * HH / 8 + 255) / 256, 256, 0, stream>>>(x, xb);
    combw_kernel<<<(3 * 16384 + 255) / 256, 256, 0, stream>>>(W1, b1, Wr1, br1, W2, b2, Wr, br, Wpack, bc);

    // deterministic two-phase partition (replaces hist + atomic csrfill)
    partA1_kernel<<<NCHUNK, 256, 0, stream>>>(ei, cc);
    partA2_kernel<<<NBUCKET, 256, 0, stream>>>(cc, tot);
    scanB_kernel<<<1, 64, 0, stream>>>(tot, bb);
    partA3_kernel<<<NCHUNK, 256, 0, stream>>>(ei, cc, bb, eb_dst, eb_src);
    partB1_kernel<<<NBUCKET, 256, 0, stream>>>(eb_dst, bb, cnt);
    deg_kernel<<<512, 256, 0, stream>>>(cnt, dinv, selfn);
    const int NB = (NN + 1023) / 1024;  // 98
    scan1_kernel<<<NB, 256, 0, stream>>>(cnt, bsum);
    scan2_kernel<<<1, 64, 0, stream>>>(bsum, NB);
    scan3_kernel<<<NB, 256, 0, stream>>>(cnt, bsum, offs);
    partB2_kernel<<<NBUCKET, 256, 0, stream>>>(eb_dst, eb_src, bb, offs, dinv, csrc, cw);

    const int GEMM_BLOCKS = (NN + 63) / 64;
    const int AGG_BLOCKS = (NN + 15) / 16;
    // layer 0
    gemm_mfma_kernel<<<GEMM_BLOCKS, 256, 0, stream>>>(xb, Wpack, bufT, NN);
    agg_relu_kernel<<<AGG_BLOCKS, 256, 0, stream>>>(bufT, offs, csrc, cw, selfn, bc, bufH);
    // layer 1
    gemm_mfma_kernel<<<GEMM_BLOCKS, 256, 0, stream>>>(bufH, Wpack + 16384, bufT, NN);
    agg_relu_kernel<<<AGG_BLOCKS, 256, 0, stream>>>(bufT, offs, csrc, cw, selfn, bc + HH, bufH);
    // layer 2
    gemm_mfma_kernel<<<GEMM_BLOCKS, 256, 0, stream>>>(bufH, Wpack + 2 * 16384, bufT, NN);
    agg_relu_kernel<<<AGG_BLOCKS, 256, 0, stream>>>(bufT, offs, csrc, cw, selfn, bc + 2 * HH, bufH);

    // pooling + readout
    poolcnt_bs_kernel<<<1, 64, 0, stream>>>(bat, pcnt);
    poolsum_kernel<<<(NN + 255) / 256, 128, 0, stream>>>(bufH, bat, psum);
    mlp_kernel<<<GG, 128, 0, stream>>>(psum, pcnt, Wl1, bl1, Wl2, bl2, out);
}

// Round 8
// 390.956 us; speedup vs baseline: 1.4009x; 1.1671x over previous
//
#include <hip/hip_runtime.h>
#include <hip/hip_bf16.h>

#define NN 100000
#define NE 1600000
#define FF 128
#define HH 128
#define CC 10
#define GG 64

#define NCHUNK 2048
#define CE 782            // ceil(NE/NCHUNK)
#define NBUCKET 128
#define BSPAN 782         // ceil(NN/NBUCKET)

typedef __attribute__((ext_vector_type(8))) short short8;
typedef __attribute__((ext_vector_type(8))) unsigned short ushort8;
typedef __attribute__((ext_vector_type(4))) float f32x4;

__device__ inline float bf2f(unsigned short u) {
    union { unsigned int i; float f; } x;
    x.i = ((unsigned int)u) << 16;
    return x.f;
}
__device__ inline unsigned short f2bf(float f) {
    union { float f; unsigned int i; } x;
    x.f = f;
    unsigned int r = x.i + 0x7FFF + ((x.i >> 16) & 1);  // RNE
    return (unsigned short)(r >> 16);
}

// ---------------- f32 -> bf16 bulk convert ----------------
__global__ __launch_bounds__(256) void f2bf_kernel(const float* __restrict__ x,
                                                   unsigned short* __restrict__ xb) {
    int i = blockIdx.x * blockDim.x + threadIdx.x;
    if (i >= NN * HH / 8) return;
    float4 v0 = ((const float4*)x)[i * 2];
    float4 v1 = ((const float4*)x)[i * 2 + 1];
    ushort8 o;
    o[0] = f2bf(v0.x); o[1] = f2bf(v0.y); o[2] = f2bf(v0.z); o[3] = f2bf(v0.w);
    o[4] = f2bf(v1.x); o[5] = f2bf(v1.y); o[6] = f2bf(v1.z); o[7] = f2bf(v1.w);
    ((ushort8*)xb)[i] = o;
}

// ---------------- weight combine + pack into MFMA B-fragment order ----------------
__global__ void combw_kernel(const float* __restrict__ W1, const float* __restrict__ b1,
                             const float* __restrict__ Wr1, const float* __restrict__ br1,
                             const float* __restrict__ W2, const float* __restrict__ b2,
                             const float* __restrict__ Wr, const float* __restrict__ br,
                             unsigned short* __restrict__ Wpack, float* __restrict__ bc) {
    int idx = blockIdx.x * blockDim.x + threadIdx.x;
    if (idx >= 3 * 16384) return;
    int l = idx / 16384, rem = idx % 16384;
    int cb = rem / 2048;
    int kb = (rem / 512) % 4;
    int lane = (rem / 8) % 64;
    int j = rem % 8;
    int k = kb * 32 + (lane >> 4) * 8 + j;
    int c = cb * 16 + (lane & 15);
    int wi = k * HH + c;
    float v = (l == 0) ? 0.95f * W1[wi] + 0.05f * Wr1[wi]
                       : 0.95f * W2[(l - 1) * 16384 + wi] + 0.05f * Wr[wi];
    Wpack[idx] = f2bf(v);
    if (rem < HH) {
        bc[l * HH + rem] = (l == 0) ? 0.95f * b1[rem] + 0.05f * br1[rem]
                                    : 0.95f * b2[(l - 1) * HH + rem] + 0.05f * br[rem];
    }
}

// ============ Phase A: deterministic edge partition by dst bucket ============
__global__ __launch_bounds__(256) void partA1_kernel(const int* __restrict__ ei,
                                                     int* __restrict__ cc) {
    __shared__ int h[NBUCKET];
    int c = blockIdx.x, t = threadIdx.x;
    if (t < NBUCKET) h[t] = 0;
    __syncthreads();
    int beg = c * CE, end = min(beg + CE, NE);
    for (int e = beg + t; e < end; e += 256) {
        int d = ei[NE + e];
        atomicAdd(&h[d / BSPAN], 1);
    }
    __syncthreads();
    if (t < NBUCKET) cc[c * NBUCKET + t] = h[t];
}

__global__ __launch_bounds__(256) void partA2_kernel(int* __restrict__ cc,
                                                     int* __restrict__ tot) {
    __shared__ int sh[256];
    int b = blockIdx.x, t = threadIdx.x;
    int v[8]; int s = 0;
#pragma unroll
    for (int i = 0; i < 8; ++i) { v[i] = cc[(t * 8 + i) * NBUCKET + b]; s += v[i]; }
    sh[t] = s; __syncthreads();
    for (int off = 1; off < 256; off <<= 1) {
        int x = (t >= off) ? sh[t - off] : 0; __syncthreads();
        sh[t] += x; __syncthreads();
    }
    int excl = sh[t] - s;
#pragma unroll
    for (int i = 0; i < 8; ++i) {
        cc[(t * 8 + i) * NBUCKET + b] = excl;
        excl += v[i];
    }
    if (t == 255) tot[b] = sh[255];
}

__global__ void scanB_kernel(const int* __restrict__ tot, int* __restrict__ bb) {
    if (threadIdx.x == 0 && blockIdx.x == 0) {
        int run = 0;
        for (int b = 0; b < NBUCKET; ++b) { bb[b] = run; run += tot[b]; }
        bb[NBUCKET] = run;
    }
}

__global__ __launch_bounds__(256) void partA3_kernel(const int* __restrict__ ei,
                                                     const int* __restrict__ cc,
                                                     const int* __restrict__ bb,
                                                     int* __restrict__ eb_dst,
                                                     int* __restrict__ eb_src) {
    __shared__ int cur[NBUCKET];
    int c = blockIdx.x, t = threadIdx.x;
    if (t < NBUCKET) cur[t] = bb[t] + cc[c * NBUCKET + t];
    __syncthreads();
    int beg = c * CE, end = min(beg + CE, NE);
    for (int e = beg + t; e < end; e += 256) {
        int d = ei[NE + e];
        int s = ei[e];
        int p = atomicAdd(&cur[d / BSPAN], 1);
        eb_dst[p] = d;
        eb_src[p] = s;
    }
}

__global__ __launch_bounds__(256) void partB1_kernel(const int* __restrict__ eb_dst,
                                                     const int* __restrict__ bb,
                                                     int* __restrict__ cnt) {
    __shared__ int h[BSPAN];
    int b = blockIdx.x, t = threadIdx.x;
    int lo = b * BSPAN;
    int span = min(BSPAN, NN - lo);
    if (span <= 0) return;
    for (int i = t; i < span; i += 256) h[i] = 0;
    __syncthreads();
    int beg = bb[b], end = bb[b + 1];
    for (int e = beg + t; e < end; e += 256)
        atomicAdd(&h[eb_dst[e] - lo], 1);
    __syncthreads();
    for (int i = t; i < span; i += 256) cnt[lo + i] = h[i];
}

__global__ void deg_kernel(const int* __restrict__ cnt, float* __restrict__ dinv,
                           float* __restrict__ selfn) {
    int stride = gridDim.x * blockDim.x;
    for (int n = blockIdx.x * blockDim.x + threadIdx.x; n < NN; n += stride) {
        float dg = (float)cnt[n] + 1.0f;
        dinv[n] = rsqrtf(dg);
        selfn[n] = 1.0f / dg;
    }
}

// ---------------- 3-kernel exclusive scan of cnt -> offs ----------------
__global__ __launch_bounds__(256) void scan1_kernel(const int* __restrict__ cnt, int* __restrict__ bsum) {
    __shared__ int sh[256];
    int b = blockIdx.x, t = threadIdx.x;
    int base = b * 1024 + t * 4;
    int s = 0;
#pragma unroll
    for (int j = 0; j < 4; ++j) { int i = base + j; if (i < NN) s += cnt[i]; }
    sh[t] = s; __syncthreads();
    for (int off = 128; off; off >>= 1) { if (t < off) sh[t] += sh[t + off]; __syncthreads(); }
    if (t == 0) bsum[b] = sh[0];
}

__global__ void scan2_kernel(int* __restrict__ bsum, int nb) {
    if (threadIdx.x == 0 && blockIdx.x == 0) {
        int run = 0;
        for (int i = 0; i < nb; ++i) { int v = bsum[i]; bsum[i] = run; run += v; }
    }
}

__global__ __launch_bounds__(256) void scan3_kernel(const int* __restrict__ cnt, const int* __restrict__ bsum,
                                                    int* __restrict__ offs) {
    __shared__ int sh[256];
    int b = blockIdx.x, t = threadIdx.x;
    int base = b * 1024 + t * 4;
    int v[4]; int s = 0;
#pragma unroll
    for (int j = 0; j < 4; ++j) { int i = base + j; v[j] = (i < NN) ? cnt[i] : 0; s += v[j]; }
    sh[t] = s; __syncthreads();
    for (int off = 1; off < 256; off <<= 1) {
        int x = (t >= off) ? sh[t - off] : 0; __syncthreads();
        sh[t] += x; __syncthreads();
    }
    int excl = sh[t] - s + bsum[b];
#pragma unroll
    for (int j = 0; j < 4; ++j) {
        int i = base + j;
        if (i < NN) { offs[i] = excl; excl += v[j]; }
    }
    if (b == 0 && t == 0) offs[NN] = NE;
}

// B2: final CSR fill from bucketed edges; LDS cursors + LDS dinv slice.
__global__ __launch_bounds__(256) void partB2_kernel(const int* __restrict__ eb_dst,
                                                     const int* __restrict__ eb_src,
                                                     const int* __restrict__ bb,
                                                     const int* __restrict__ offs,
                                                     const float* __restrict__ dinv,
                                                     int* __restrict__ csrc,
                                                     float* __restrict__ cw) {
    __shared__ int lcur[BSPAN];
    __shared__ float ldinv[BSPAN];
    int b = blockIdx.x, t = threadIdx.x;
    int lo = b * BSPAN;
    int span = min(BSPAN, NN - lo);
    if (span <= 0) return;
    for (int i = t; i < span; i += 256) {
        lcur[i] = offs[lo + i];
        ldinv[i] = dinv[lo + i];
    }
    __syncthreads();
    int beg = bb[b], end = bb[b + 1];
    for (int e = beg + t; e < end; e += 256) {
        int d = eb_dst[e] - lo;
        int s = eb_src[e];
        int p = atomicAdd(&lcur[d], 1);
        csrc[p] = s;
        cw[p] = dinv[s] * ldinv[d];
    }
}

// ---------------- MFMA GEMM: out[N,128](bf16) = A[N,128](bf16) @ Wc ----------------
__global__ __launch_bounds__(256) void gemm_mfma_kernel(const unsigned short* __restrict__ A,
                                                        const unsigned short* __restrict__ Wp,
                                                        unsigned short* __restrict__ out,
                                                        int nrows) {
    int w = threadIdx.x >> 6;
    int l = threadIdx.x & 63;
    int m0 = blockIdx.x * 64 + w * 16;
    int kg = l >> 4;
    int cl = l & 15;
    int arow = m0 + cl;

    short8 a[4];
    if (arow < nrows) {
        const short8* Ar = (const short8*)(A + (size_t)arow * HH);
#pragma unroll
        for (int kb = 0; kb < 4; ++kb) a[kb] = Ar[kb * 4 + kg];
    } else {
        short8 z = {};
#pragma unroll
        for (int kb = 0; kb < 4; ++kb) a[kb] = z;
    }

#pragma unroll
    for (int cb = 0; cb < 8; ++cb) {
        f32x4 acc = {0.f, 0.f, 0.f, 0.f};
#pragma unroll
        for (int kb = 0; kb < 4; ++kb) {
            short8 b = *(const short8*)(Wp + (size_t)(cb * 4 + kb) * 512 + l * 8);
            acc = __builtin_amdgcn_mfma_f32_16x16x32_bf16(a[kb], b, acc, 0, 0, 0);
        }
#pragma unroll
        for (int r = 0; r < 4; ++r) {
            int orow = m0 + kg * 4 + r;
            if (orow < nrows) out[(size_t)orow * HH + cb * 16 + cl] = f2bf(acc[r]);
        }
    }
}

// ---------- aggregation + self + bias + relu (bf16 rows, 16 lanes/node) ----------
__global__ __launch_bounds__(256) void agg_relu_kernel(const unsigned short* __restrict__ hT,
                                                       const int* __restrict__ offs,
                                                       const int* __restrict__ csrc,
                                                       const float* __restrict__ cw,
                                                       const float* __restrict__ selfn,
                                                       const float* __restrict__ bias,
                                                       unsigned short* __restrict__ hOut) {
    int n = blockIdx.x * 16 + (threadIdx.x >> 4);
    if (n >= NN) return;
    int lane = threadIdx.x & 15;
    int beg = offs[n], end = offs[n + 1];
    const ushort8* h8 = (const ushort8*)hT;
    float acc[8] = {};
    int e = beg;
    for (; e + 3 < end; e += 4) {
        int s0 = csrc[e], s1 = csrc[e + 1], s2 = csrc[e + 2], s3 = csrc[e + 3];
        float w0 = cw[e], w1 = cw[e + 1], w2 = cw[e + 2], w3 = cw[e + 3];
        ushort8 v0 = h8[(size_t)s0 * 16 + lane];
        ushort8 v1 = h8[(size_t)s1 * 16 + lane];
        ushort8 v2 = h8[(size_t)s2 * 16 + lane];
        ushort8 v3 = h8[(size_t)s3 * 16 + lane];
#pragma unroll
        for (int j = 0; j < 8; ++j) {
            acc[j] = fmaf(bf2f(v0[j]), w0, acc[j]);
            acc[j] = fmaf(bf2f(v1[j]), w1, acc[j]);
            acc[j] = fmaf(bf2f(v2[j]), w2, acc[j]);
            acc[j] = fmaf(bf2f(v3[j]), w3, acc[j]);
        }
    }
    for (; e < end; ++e) {
        int s = csrc[e];
        float w = cw[e];
        ushort8 v = h8[(size_t)s * 16 + lane];
#pragma unroll
        for (int j = 0; j < 8; ++j) acc[j] = fmaf(bf2f(v[j]), w, acc[j]);
    }
    float sn = selfn[n];
    ushort8 hv = h8[(size_t)n * 16 + lane];
    float4 bv0 = ((const float4*)bias)[lane * 2];
    float4 bv1 = ((const float4*)bias)[lane * 2 + 1];
    float bb[8] = {bv0.x, bv0.y, bv0.z, bv0.w, bv1.x, bv1.y, bv1.z, bv1.w};
    ushort8 o;
#pragma unroll
    for (int j = 0; j < 8; ++j) {
        float v = fmaxf(acc[j] + bf2f(hv[j]) * sn + bb[j], 0.f);
        o[j] = f2bf(v);
    }
    ((ushort8*)hOut)[(size_t)n * 16 + lane] = o;
}

// -------- pooling: 4 segments/graph, vectorized, LDS reduce, few atomics --------
// Also writes pcnt (graph row-count) from segment 0.
__global__ __launch_bounds__(256) void poolsum2_kernel(const unsigned short* __restrict__ h,
                                                       const int* __restrict__ batch,
                                                       float* __restrict__ psum,
                                                       int* __restrict__ pcnt) {
    int g = blockIdx.x >> 2;
    int seg = blockIdx.x & 3;
    int t = threadIdx.x;
    // binary search graph bounds (batch sorted); uniform across block
    int lo = 0, hi = NN;
    while (lo < hi) { int m = (lo + hi) >> 1; if (batch[m] < g) lo = m + 1; else hi = m; }
    int lb = lo;
    lo = 0; hi = NN;
    while (lo < hi) { int m = (lo + hi) >> 1; if (batch[m] <= g) lo = m + 1; else hi = m; }
    int ub = lo;
    int len = ub - lb;
    if (seg == 0 && t == 0) pcnt[g] = len;
    int b0 = lb + (int)(((long long)len * seg) / 4);
    int b1 = lb + (int)(((long long)len * (seg + 1)) / 4);

    int fg = t & 15;        // feature group: features fg*8 .. fg*8+7
    int rg = t >> 4;        // row slot 0..15
    const ushort8* h8 = (const ushort8*)h;
    float acc[8] = {};
    for (int n = b0 + rg; n < b1; n += 16) {
        ushort8 v = h8[(size_t)n * 16 + fg];
#pragma unroll
        for (int j = 0; j < 8; ++j) acc[j] += bf2f(v[j]);
    }
    __shared__ float red[256][8];
#pragma unroll
    for (int j = 0; j < 8; ++j) red[t][j] = acc[j];
    __syncthreads();
    for (int off = 128; off >= 16; off >>= 1) {
        if (t < off) {
#pragma unroll
            for (int j = 0; j < 8; ++j) red[t][j] += red[t + off][j];
        }
        __syncthreads();
    }
    if (t < 16) {
#pragma unroll
        for (int j = 0; j < 8; ++j)
            atomicAdd(&psum[g * HH + t * 8 + j], red[t][j]);
    }
}

// ---------------- readout MLP + log_softmax ----------------
__global__ __launch_bounds__(128) void mlp_kernel(const float* __restrict__ psum,
                                                  const int* __restrict__ pcnt,
                                                  const float* __restrict__ Wl1,
                                                  const float* __restrict__ bl1,
                                                  const float* __restrict__ Wl2,
                                                  const float* __restrict__ bl2,
                                                  float* __restrict__ out) {
    __shared__ float p[128], o1[128], lg[CC];
    int g = blockIdx.x, t = threadIdx.x;
    float cnt = fmaxf((float)pcnt[g], 1.0f);
    p[t] = psum[g * HH + t] / cnt;
    __syncthreads();
    float acc = bl1[t];
    for (int k = 0; k < HH; ++k) acc = fmaf(p[k], Wl1[k * HH + t], acc);
    o1[t] = fmaxf(acc, 0.f);
    __syncthreads();
    if (t < CC) {
        float a2 = bl2[t];
        for (int j = 0; j < HH; ++j) a2 = fmaf(o1[j], Wl2[j * CC + t], a2);
        lg[t] = a2;
    }
    __syncthreads();
    if (t == 0) {
        float m = lg[0];
        for (int c = 1; c < CC; ++c) m = fmaxf(m, lg[c]);
        float s = 0.f;
        for (int c = 0; c < CC; ++c) s += expf(lg[c] - m);
        float ls = logf(s);
        for (int c = 0; c < CC; ++c) out[g * CC + c] = lg[c] - m - ls;
    }
}

extern "C" void kernel_launch(void* const* d_in, const int* in_sizes, int n_in,
                              void* d_out, int out_size, void* d_ws, size_t ws_size,
                              hipStream_t stream) {
    const float* x   = (const float*)d_in[0];
    const int*   ei  = (const int*)d_in[1];
    const int*   bat = (const int*)d_in[2];
    const float* W1  = (const float*)d_in[3];
    const float* b1  = (const float*)d_in[4];
    const float* Wr1 = (const float*)d_in[5];
    const float* br1 = (const float*)d_in[6];
    const float* W2  = (const float*)d_in[7];
    const float* b2  = (const float*)d_in[8];
    const float* Wr  = (const float*)d_in[9];
    const float* br  = (const float*)d_in[10];
    const float* Wl1 = (const float*)d_in[11];
    const float* bl1 = (const float*)d_in[12];
    const float* Wl2 = (const float*)d_in[13];
    const float* bl2 = (const float*)d_in[14];
    float* out = (float*)d_out;

    // workspace carve-up (256B aligned)
    char* base = (char*)d_ws;
    size_t off = 0;
    auto alloc = [&](size_t bytes) {
        void* p = base + off;
        off += (bytes + 255) & ~(size_t)255;
        return p;
    };
    unsigned short* xb   = (unsigned short*)alloc((size_t)NN * HH * 2);
    unsigned short* bufT = (unsigned short*)alloc((size_t)NN * HH * 2);
    unsigned short* bufH = (unsigned short*)alloc((size_t)NN * HH * 2);
    int*   csrc   = (int*)alloc((size_t)NE * 4);
    float* cw     = (float*)alloc((size_t)NE * 4);
    int*   offs   = (int*)alloc((size_t)(NN + 1) * 4);
    int*   cnt    = (int*)alloc((size_t)NN * 4);
    float* dinv   = (float*)alloc((size_t)NN * 4);
    float* selfn  = (float*)alloc((size_t)NN * 4);
    int*   bsum   = (int*)alloc(128 * 4);
    unsigned short* Wpack = (unsigned short*)alloc(3 * 16384 * 2);
    float* bc     = (float*)alloc(3 * HH * 4);
    float* psum   = (float*)alloc(GG * HH * 4);
    int*   pcnt   = (int*)alloc(GG * 4);
    int*   tot    = (int*)alloc(NBUCKET * 4);
    int*   bb     = (int*)alloc((NBUCKET + 1) * 4);
    int* eb_dst = (int*)bufT;
    int* eb_src = (int*)bufT + NE;
    int* cc     = (int*)bufH;
    (void)ws_size; (void)in_sizes; (void)n_in; (void)out_size;

    hipMemsetAsync(psum, 0, (size_t)GG * HH * 4, stream);

    // input convert + combined packed weights
    f2bf_kernel<<<(NN * HH / 8 + 255) / 256, 256, 0, stream>>>(x, xb);
    combw_kernel<<<(3 * 16384 + 255) / 256, 256, 0, stream>>>(W1, b1, Wr1, br1, W2, b2, Wr, br, Wpack, bc);

    // deterministic two-phase partition
    partA1_kernel<<<NCHUNK, 256, 0, stream>>>(ei, cc);
    partA2_kernel<<<NBUCKET, 256, 0, stream>>>(cc, tot);
    scanB_kernel<<<1, 64, 0, stream>>>(tot, bb);
    partA3_kernel<<<NCHUNK, 256, 0, stream>>>(ei, cc, bb, eb_dst, eb_src);
    partB1_kernel<<<NBUCKET, 256, 0, stream>>>(eb_dst, bb, cnt);
    deg_kernel<<<512, 256, 0, stream>>>(cnt, dinv, selfn);
    const int NB = (NN + 1023) / 1024;  // 98
    scan1_kernel<<<NB, 256, 0, stream>>>(cnt, bsum);
    scan2_kernel<<<1, 64, 0, stream>>>(bsum, NB);
    scan3_kernel<<<NB, 256, 0, stream>>>(cnt, bsum, offs);
    partB2_kernel<<<NBUCKET, 256, 0, stream>>>(eb_dst, eb_src, bb, offs, dinv, csrc, cw);

    const int GEMM_BLOCKS = (NN + 63) / 64;
    const int AGG_BLOCKS = (NN + 15) / 16;
    // layer 0
    gemm_mfma_kernel<<<GEMM_BLOCKS, 256, 0, stream>>>(xb, Wpack, bufT, NN);
    agg_relu_kernel<<<AGG_BLOCKS, 256, 0, stream>>>(bufT, offs, csrc, cw, selfn, bc, bufH);
    // layer 1
    gemm_mfma_kernel<<<GEMM_BLOCKS, 256, 0, stream>>>(bufH, Wpack + 16384, bufT, NN);
    agg_relu_kernel<<<AGG_BLOCKS, 256, 0, stream>>>(bufT, offs, csrc, cw, selfn, bc + HH, bufH);
    // layer 2
    gemm_mfma_kernel<<<GEMM_BLOCKS, 256, 0, stream>>>(bufH, Wpack + 2 * 16384, bufT, NN);
    agg_relu_kernel<<<AGG_BLOCKS, 256, 0, stream>>>(bufT, offs, csrc, cw, selfn, bc + 2 * HH, bufH);

    // pooling + readout
    poolsum2_kernel<<<GG * 4, 256, 0, stream>>>(bufH, bat, psum, pcnt);
    mlp_kernel<<<GG, 128, 0, stream>>>(psum, pcnt, Wl1, bl1, Wl2, bl2, out);
}

// Round 9
// 325.663 us; speedup vs baseline: 1.6817x; 1.2005x over previous
//
#include <hip/hip_runtime.h>
#include <hip/hip_bf16.h>
#include <hip/hip_fp8.h>

#define NN 100000
#define NE 1600000
#define FF 128
#define HH 128
#define CC 10
#define GG 64

#define NCHUNK 2048
#define CE 782            // ceil(NE/NCHUNK)
#define NBUCKET 128
#define BSPAN 782         // ceil(NN/NBUCKET)

typedef __attribute__((ext_vector_type(8))) short short8;
typedef __attribute__((ext_vector_type(8))) unsigned short ushort8;
typedef __attribute__((ext_vector_type(4))) float f32x4;

__device__ inline float bf2f(unsigned short u) {
    union { unsigned int i; float f; } x;
    x.i = ((unsigned int)u) << 16;
    return x.f;
}
__device__ inline unsigned short f2bf(float f) {
    union { float f; unsigned int i; } x;
    x.f = f;
    unsigned int r = x.i + 0x7FFF + ((x.i >> 16) & 1);  // RNE
    return (unsigned short)(r >> 16);
}
__device__ inline unsigned char f8enc(float v) {
    __hip_fp8_e4m3 q(v);
    return (unsigned char)q.__x;
}
__device__ inline float f8dec(unsigned char b) {
    __hip_fp8_e4m3 q;
    q.__x = (__hip_fp8_storage_t)b;
    return (float)q;
}

// ---------------- f32 -> bf16 bulk convert ----------------
__global__ __launch_bounds__(256) void f2bf_kernel(const float* __restrict__ x,
                                                   unsigned short* __restrict__ xb) {
    int i = blockIdx.x * blockDim.x + threadIdx.x;
    if (i >= NN * HH / 8) return;
    float4 v0 = ((const float4*)x)[i * 2];
    float4 v1 = ((const float4*)x)[i * 2 + 1];
    ushort8 o;
    o[0] = f2bf(v0.x); o[1] = f2bf(v0.y); o[2] = f2bf(v0.z); o[3] = f2bf(v0.w);
    o[4] = f2bf(v1.x); o[5] = f2bf(v1.y); o[6] = f2bf(v1.z); o[7] = f2bf(v1.w);
    ((ushort8*)xb)[i] = o;
}

// ---------------- weight combine + pack into MFMA B-fragment order ----------------
__global__ void combw_kernel(const float* __restrict__ W1, const float* __restrict__ b1,
                             const float* __restrict__ Wr1, const float* __restrict__ br1,
                             const float* __restrict__ W2, const float* __restrict__ b2,
                             const float* __restrict__ Wr, const float* __restrict__ br,
                             unsigned short* __restrict__ Wpack, float* __restrict__ bc) {
    int idx = blockIdx.x * blockDim.x + threadIdx.x;
    if (idx >= 3 * 16384) return;
    int l = idx / 16384, rem = idx % 16384;
    int cb = rem / 2048;
    int kb = (rem / 512) % 4;
    int lane = (rem / 8) % 64;
    int j = rem % 8;
    int k = kb * 32 + (lane >> 4) * 8 + j;
    int c = cb * 16 + (lane & 15);
    int wi = k * HH + c;
    float v = (l == 0) ? 0.95f * W1[wi] + 0.05f * Wr1[wi]
                       : 0.95f * W2[(l - 1) * 16384 + wi] + 0.05f * Wr[wi];
    Wpack[idx] = f2bf(v);
    if (rem < HH) {
        bc[l * HH + rem] = (l == 0) ? 0.95f * b1[rem] + 0.05f * br1[rem]
                                    : 0.95f * b2[(l - 1) * HH + rem] + 0.05f * br[rem];
    }
}

// ============ Phase A: deterministic edge partition by dst bucket ============
__global__ __launch_bounds__(256) void partA1_kernel(const int* __restrict__ ei,
                                                     int* __restrict__ cc) {
    __shared__ int h[NBUCKET];
    int c = blockIdx.x, t = threadIdx.x;
    if (t < NBUCKET) h[t] = 0;
    __syncthreads();
    int beg = c * CE, end = min(beg + CE, NE);
    for (int e = beg + t; e < end; e += 256) {
        int d = ei[NE + e];
        atomicAdd(&h[d / BSPAN], 1);
    }
    __syncthreads();
    if (t < NBUCKET) cc[c * NBUCKET + t] = h[t];
}

__global__ __launch_bounds__(256) void partA2_kernel(int* __restrict__ cc,
                                                     int* __restrict__ tot) {
    __shared__ int sh[256];
    int b = blockIdx.x, t = threadIdx.x;
    int v[8]; int s = 0;
#pragma unroll
    for (int i = 0; i < 8; ++i) { v[i] = cc[(t * 8 + i) * NBUCKET + b]; s += v[i]; }
    sh[t] = s; __syncthreads();
    for (int off = 1; off < 256; off <<= 1) {
        int x = (t >= off) ? sh[t - off] : 0; __syncthreads();
        sh[t] += x; __syncthreads();
    }
    int excl = sh[t] - s;
#pragma unroll
    for (int i = 0; i < 8; ++i) {
        cc[(t * 8 + i) * NBUCKET + b] = excl;
        excl += v[i];
    }
    if (t == 255) tot[b] = sh[255];
}

__global__ void scanB_kernel(const int* __restrict__ tot, int* __restrict__ bb) {
    if (threadIdx.x == 0 && blockIdx.x == 0) {
        int run = 0;
        for (int b = 0; b < NBUCKET; ++b) { bb[b] = run; run += tot[b]; }
        bb[NBUCKET] = run;
    }
}

__global__ __launch_bounds__(256) void partA3_kernel(const int* __restrict__ ei,
                                                     const int* __restrict__ cc,
                                                     const int* __restrict__ bb,
                                                     int* __restrict__ eb_dst,
                                                     int* __restrict__ eb_src) {
    __shared__ int cur[NBUCKET];
    int c = blockIdx.x, t = threadIdx.x;
    if (t < NBUCKET) cur[t] = bb[t] + cc[c * NBUCKET + t];
    __syncthreads();
    int beg = c * CE, end = min(beg + CE, NE);
    for (int e = beg + t; e < end; e += 256) {
        int d = ei[NE + e];
        int s = ei[e];
        int p = atomicAdd(&cur[d / BSPAN], 1);
        eb_dst[p] = d;
        eb_src[p] = s;
    }
}

__global__ __launch_bounds__(256) void partB1_kernel(const int* __restrict__ eb_dst,
                                                     const int* __restrict__ bb,
                                                     int* __restrict__ cnt) {
    __shared__ int h[BSPAN];
    int b = blockIdx.x, t = threadIdx.x;
    int lo = b * BSPAN;
    int span = min(BSPAN, NN - lo);
    if (span <= 0) return;
    for (int i = t; i < span; i += 256) h[i] = 0;
    __syncthreads();
    int beg = bb[b], end = bb[b + 1];
    for (int e = beg + t; e < end; e += 256)
        atomicAdd(&h[eb_dst[e] - lo], 1);
    __syncthreads();
    for (int i = t; i < span; i += 256) cnt[lo + i] = h[i];
}

__global__ void deg_kernel(const int* __restrict__ cnt, float* __restrict__ dinv,
                           float* __restrict__ selfn) {
    int stride = gridDim.x * blockDim.x;
    for (int n = blockIdx.x * blockDim.x + threadIdx.x; n < NN; n += stride) {
        float dg = (float)cnt[n] + 1.0f;
        dinv[n] = rsqrtf(dg);
        selfn[n] = 1.0f / dg;
    }
}

// ---------------- 3-kernel exclusive scan of cnt -> offs ----------------
__global__ __launch_bounds__(256) void scan1_kernel(const int* __restrict__ cnt, int* __restrict__ bsum) {
    __shared__ int sh[256];
    int b = blockIdx.x, t = threadIdx.x;
    int base = b * 1024 + t * 4;
    int s = 0;
#pragma unroll
    for (int j = 0; j < 4; ++j) { int i = base + j; if (i < NN) s += cnt[i]; }
    sh[t] = s; __syncthreads();
    for (int off = 128; off; off >>= 1) { if (t < off) sh[t] += sh[t + off]; __syncthreads(); }
    if (t == 0) bsum[b] = sh[0];
}

__global__ void scan2_kernel(int* __restrict__ bsum, int nb) {
    if (threadIdx.x == 0 && blockIdx.x == 0) {
        int run = 0;
        for (int i = 0; i < nb; ++i) { int v = bsum[i]; bsum[i] = run; run += v; }
    }
}

__global__ __launch_bounds__(256) void scan3_kernel(const int* __restrict__ cnt, const int* __restrict__ bsum,
                                                    int* __restrict__ offs) {
    __shared__ int sh[256];
    int b = blockIdx.x, t = threadIdx.x;
    int base = b * 1024 + t * 4;
    int v[4]; int s = 0;
#pragma unroll
    for (int j = 0; j < 4; ++j) { int i = base + j; v[j] = (i < NN) ? cnt[i] : 0; s += v[j]; }
    sh[t] = s; __syncthreads();
    for (int off = 1; off < 256; off <<= 1) {
        int x = (t >= off) ? sh[t - off] : 0; __syncthreads();
        sh[t] += x; __syncthreads();
    }
    int excl = sh[t] - s + bsum[b];
#pragma unroll
    for (int j = 0; j < 4; ++j) {
        int i = base + j;
        if (i < NN) { offs[i] = excl; excl += v[j]; }
    }
    if (b == 0 && t == 0) offs[NN] = NE;
}

// B2: final CSR fill from bucketed edges; LDS cursors + LDS dinv slice.
__global__ __launch_bounds__(256) void partB2_kernel(const int* __restrict__ eb_dst,
                                                     const int* __restrict__ eb_src,
                                                     const int* __restrict__ bb,
                                                     const int* __restrict__ offs,
                                                     const float* __restrict__ dinv,
                                                     int* __restrict__ csrc,
                                                     float* __restrict__ cw) {
    __shared__ int lcur[BSPAN];
    __shared__ float ldinv[BSPAN];
    int b = blockIdx.x, t = threadIdx.x;
    int lo = b * BSPAN;
    int span = min(BSPAN, NN - lo);
    if (span <= 0) return;
    for (int i = t; i < span; i += 256) {
        lcur[i] = offs[lo + i];
        ldinv[i] = dinv[lo + i];
    }
    __syncthreads();
    int beg = bb[b], end = bb[b + 1];
    for (int e = beg + t; e < end; e += 256) {
        int d = eb_dst[e] - lo;
        int s = eb_src[e];
        int p = atomicAdd(&lcur[d], 1);
        csrc[p] = s;
        cw[p] = dinv[s] * ldinv[d];
    }
}

// ------- MFMA GEMM: t8[N,128](fp8 e4m3) = A[N,128](bf16) @ Wc -------
// fp8 output via 8KB LDS transpose (MFMA D-layout bytes are stride-16 per thread)
__global__ __launch_bounds__(256) void gemm_mfma_kernel(const unsigned short* __restrict__ A,
                                                        const unsigned short* __restrict__ Wp,
                                                        unsigned char* __restrict__ out8,
                                                        int nrows) {
    __shared__ unsigned char f8s[64][128];
    int w = threadIdx.x >> 6;
    int l = threadIdx.x & 63;
    int m0 = blockIdx.x * 64 + w * 16;
    int kg = l >> 4;
    int cl = l & 15;
    int arow = m0 + cl;

    short8 a[4];
    if (arow < nrows) {
        const short8* Ar = (const short8*)(A + (size_t)arow * HH);
#pragma unroll
        for (int kb = 0; kb < 4; ++kb) a[kb] = Ar[kb * 4 + kg];
    } else {
        short8 z = {};
#pragma unroll
        for (int kb = 0; kb < 4; ++kb) a[kb] = z;
    }

#pragma unroll
    for (int cb = 0; cb < 8; ++cb) {
        f32x4 acc = {0.f, 0.f, 0.f, 0.f};
#pragma unroll
        for (int kb = 0; kb < 4; ++kb) {
            short8 b = *(const short8*)(Wp + (size_t)(cb * 4 + kb) * 512 + l * 8);
            acc = __builtin_amdgcn_mfma_f32_16x16x32_bf16(a[kb], b, acc, 0, 0, 0);
        }
#pragma unroll
        for (int r = 0; r < 4; ++r)
            f8s[w * 16 + kg * 4 + r][cb * 16 + cl] = f8enc(acc[r]);
    }
    __syncthreads();
    int blk0 = blockIdx.x * 64;
    for (int u = threadIdx.x; u < 512; u += 256) {       // 64 rows x 8 x 16B
        int row = u >> 3, c16 = u & 7;
        int grow = blk0 + row;
        if (grow < nrows)
            ((uint4*)out8)[(size_t)grow * 8 + c16] = ((const uint4*)&f8s[row][0])[c16];
    }
}

// ---- aggregation + self + bias + relu (fp8 gather, 16 lanes/node, bf16 out) ----
__global__ __launch_bounds__(256) void agg_relu_kernel(const unsigned char* __restrict__ t8,
                                                       const int* __restrict__ offs,
                                                       const int* __restrict__ csrc,
                                                       const float* __restrict__ cw,
                                                       const float* __restrict__ selfn,
                                                       const float* __restrict__ bias,
                                                       unsigned short* __restrict__ hOut) {
    int n = blockIdx.x * 16 + (threadIdx.x >> 4);
    if (n >= NN) return;
    int lane = threadIdx.x & 15;          // features lane*8 .. lane*8+7
    int beg = offs[n], end = offs[n + 1];
    const uint2* g8 = (const uint2*)t8;   // row = 16 uint2 (128 fp8)
    float acc[8] = {};
    int e = beg;
    for (; e + 3 < end; e += 4) {
        int s0 = csrc[e], s1 = csrc[e + 1], s2 = csrc[e + 2], s3 = csrc[e + 3];
        float w0 = cw[e], w1 = cw[e + 1], w2 = cw[e + 2], w3 = cw[e + 3];
        uint2 v0 = g8[(size_t)s0 * 16 + lane];
        uint2 v1 = g8[(size_t)s1 * 16 + lane];
        uint2 v2 = g8[(size_t)s2 * 16 + lane];
        uint2 v3 = g8[(size_t)s3 * 16 + lane];
#pragma unroll
        for (int j = 0; j < 4; ++j) {
            acc[j]     = fmaf(f8dec((v0.x >> (8 * j)) & 0xFF), w0, acc[j]);
            acc[j + 4] = fmaf(f8dec((v0.y >> (8 * j)) & 0xFF), w0, acc[j + 4]);
            acc[j]     = fmaf(f8dec((v1.x >> (8 * j)) & 0xFF), w1, acc[j]);
            acc[j + 4] = fmaf(f8dec((v1.y >> (8 * j)) & 0xFF), w1, acc[j + 4]);
            acc[j]     = fmaf(f8dec((v2.x >> (8 * j)) & 0xFF), w2, acc[j]);
            acc[j + 4] = fmaf(f8dec((v2.y >> (8 * j)) & 0xFF), w2, acc[j + 4]);
            acc[j]     = fmaf(f8dec((v3.x >> (8 * j)) & 0xFF), w3, acc[j]);
            acc[j + 4] = fmaf(f8dec((v3.y >> (8 * j)) & 0xFF), w3, acc[j + 4]);
        }
    }
    for (; e < end; ++e) {
        int s = csrc[e];
        float w = cw[e];
        uint2 v = g8[(size_t)s * 16 + lane];
#pragma unroll
        for (int j = 0; j < 4; ++j) {
            acc[j]     = fmaf(f8dec((v.x >> (8 * j)) & 0xFF), w, acc[j]);
            acc[j + 4] = fmaf(f8dec((v.y >> (8 * j)) & 0xFF), w, acc[j + 4]);
        }
    }
    float sn = selfn[n];
    uint2 hv = g8[(size_t)n * 16 + lane];
    float4 bv0 = ((const float4*)bias)[lane * 2];
    float4 bv1 = ((const float4*)bias)[lane * 2 + 1];
    float bb[8] = {bv0.x, bv0.y, bv0.z, bv0.w, bv1.x, bv1.y, bv1.z, bv1.w};
    float hs[8];
#pragma unroll
    for (int j = 0; j < 4; ++j) {
        hs[j]     = f8dec((hv.x >> (8 * j)) & 0xFF);
        hs[j + 4] = f8dec((hv.y >> (8 * j)) & 0xFF);
    }
    ushort8 o;
#pragma unroll
    for (int j = 0; j < 8; ++j) {
        float v = fmaxf(acc[j] + hs[j] * sn + bb[j], 0.f);
        o[j] = f2bf(v);
    }
    ((ushort8*)hOut)[(size_t)n * 16 + lane] = o;
}

// -------- pooling: 4 segments/graph, vectorized, LDS reduce, few atomics --------
__global__ __launch_bounds__(256) void poolsum2_kernel(const unsigned short* __restrict__ h,
                                                       const int* __restrict__ batch,
                                                       float* __restrict__ psum,
                                                       int* __restrict__ pcnt) {
    int g = blockIdx.x >> 2;
    int seg = blockIdx.x & 3;
    int t = threadIdx.x;
    int lo = 0, hi = NN;
    while (lo < hi) { int m = (lo + hi) >> 1; if (batch[m] < g) lo = m + 1; else hi = m; }
    int lb = lo;
    lo = 0; hi = NN;
    while (lo < hi) { int m = (lo + hi) >> 1; if (batch[m] <= g) lo = m + 1; else hi = m; }
    int ub = lo;
    int len = ub - lb;
    if (seg == 0 && t == 0) pcnt[g] = len;
    int b0 = lb + (int)(((long long)len * seg) / 4);
    int b1 = lb + (int)(((long long)len * (seg + 1)) / 4);

    int fg = t & 15;
    int rg = t >> 4;
    const ushort8* h8 = (const ushort8*)h;
    float acc[8] = {};
    for (int n = b0 + rg; n < b1; n += 16) {
        ushort8 v = h8[(size_t)n * 16 + fg];
#pragma unroll
        for (int j = 0; j < 8; ++j) acc[j] += bf2f(v[j]);
    }
    __shared__ float red[256][8];
#pragma unroll
    for (int j = 0; j < 8; ++j) red[t][j] = acc[j];
    __syncthreads();
    for (int off = 128; off >= 16; off >>= 1) {
        if (t < off) {
#pragma unroll
            for (int j = 0; j < 8; ++j) red[t][j] += red[t + off][j];
        }
        __syncthreads();
    }
    if (t < 16) {
#pragma unroll
        for (int j = 0; j < 8; ++j)
            atomicAdd(&psum[g * HH + t * 8 + j], red[t][j]);
    }
}

// ---------------- readout MLP + log_softmax ----------------
__global__ __launch_bounds__(128) void mlp_kernel(const float* __restrict__ psum,
                                                  const int* __restrict__ pcnt,
                                                  const float* __restrict__ Wl1,
                                                  const float* __restrict__ bl1,
                                                  const float* __restrict__ Wl2,
                                                  const float* __restrict__ bl2,
                                                  float* __restrict__ out) {
    __shared__ float p[128], o1[128], lg[CC];
    int g = blockIdx.x, t = threadIdx.x;
    float cnt = fmaxf((float)pcnt[g], 1.0f);
    p[t] = psum[g * HH + t] / cnt;
    __syncthreads();
    float acc = bl1[t];
    for (int k = 0; k < HH; ++k) acc = fmaf(p[k], Wl1[k * HH + t], acc);
    o1[t] = fmaxf(acc, 0.f);
    __syncthreads();
    if (t < CC) {
        float a2 = bl2[t];
        for (int j = 0; j < HH; ++j) a2 = fmaf(o1[j], Wl2[j * CC + t], a2);
        lg[t] = a2;
    }
    __syncthreads();
    if (t == 0) {
        float m = lg[0];
        for (int c = 1; c < CC; ++c) m = fmaxf(m, lg[c]);
        float s = 0.f;
        for (int c = 0; c < CC; ++c) s += expf(lg[c] - m);
        float ls = logf(s);
        for (int c = 0; c < CC; ++c) out[g * CC + c] = lg[c] - m - ls;
    }
}

extern "C" void kernel_launch(void* const* d_in, const int* in_sizes, int n_in,
                              void* d_out, int out_size, void* d_ws, size_t ws_size,
                              hipStream_t stream) {
    const float* x   = (const float*)d_in[0];
    const int*   ei  = (const int*)d_in[1];
    const int*   bat = (const int*)d_in[2];
    const float* W1  = (const float*)d_in[3];
    const float* b1  = (const float*)d_in[4];
    const float* Wr1 = (const float*)d_in[5];
    const float* br1 = (const float*)d_in[6];
    const float* W2  = (const float*)d_in[7];
    const float* b2  = (const float*)d_in[8];
    const float* Wr  = (const float*)d_in[9];
    const float* br  = (const float*)d_in[10];
    const float* Wl1 = (const float*)d_in[11];
    const float* bl1 = (const float*)d_in[12];
    const float* Wl2 = (const float*)d_in[13];
    const float* bl2 = (const float*)d_in[14];
    float* out = (float*)d_out;

    // workspace carve-up (256B aligned)
    char* base = (char*)d_ws;
    size_t off = 0;
    auto alloc = [&](size_t bytes) {
        void* p = base + off;
        off += (bytes + 255) & ~(size_t)255;
        return p;
    };
    unsigned short* xb   = (unsigned short*)alloc((size_t)NN * HH * 2);
    unsigned short* bufH = (unsigned short*)alloc((size_t)NN * HH * 2);
    unsigned char*  t8   = (unsigned char*)alloc((size_t)NN * HH);
    int*   csrc   = (int*)alloc((size_t)NE * 4);
    float* cw     = (float*)alloc((size_t)NE * 4);
    int*   offs   = (int*)alloc((size_t)(NN + 1) * 4);
    int*   cnt    = (int*)alloc((size_t)NN * 4);
    float* dinv   = (float*)alloc((size_t)NN * 4);
    float* selfn  = (float*)alloc((size_t)NN * 4);
    int*   bsum   = (int*)alloc(128 * 4);
    unsigned short* Wpack = (unsigned short*)alloc(3 * 16384 * 2);
    float* bc     = (float*)alloc(3 * HH * 4);
    float* psum   = (float*)alloc(GG * HH * 4);
    int*   pcnt   = (int*)alloc(GG * 4);
    int*   tot    = (int*)alloc(NBUCKET * 4);
    int*   bb     = (int*)alloc((NBUCKET + 1) * 4);
    // partition scratch aliases into bufH (dead until agg layer 0 writes it)
    int* eb_dst = (int*)bufH;                  // 6.4 MB
    int* eb_src = (int*)bufH + NE;             // 6.4 MB
    int* cc     = (int*)bufH + 2 * NE;         // 1 MB (bufH = 25.6 MB total)
    (void)ws_size; (void)in_sizes; (void)n_in; (void)out_size;

    hipMemsetAsync(psum, 0, (size_t)GG * HH * 4, stream);

    // input convert + combined packed weights
    f2bf_kernel<<<(NN * HH / 8 + 255) / 256, 256, 0, stream>>>(x, xb);
    combw_kernel<<<(3 * 16384 + 255) / 256, 256, 0, stream>>>(W1, b1, Wr1, br1, W2, b2, Wr, br, Wpack, bc);

    // deterministic two-phase partition
    partA1_kernel<<<NCHUNK, 256, 0, stream>>>(ei, cc);
    partA2_kernel<<<NBUCKET, 256, 0, stream>>>(cc, tot);
    scanB_kernel<<<1, 64, 0, stream>>>(tot, bb);
    partA3_kernel<<<NCHUNK, 256, 0, stream>>>(ei, cc, bb, eb_dst, eb_src);
    partB1_kernel<<<NBUCKET, 256, 0, stream>>>(eb_dst, bb, cnt);
    deg_kernel<<<512, 256, 0, stream>>>(cnt, dinv, selfn);
    const int NB = (NN + 1023) / 1024;  // 98
    scan1_kernel<<<NB, 256, 0, stream>>>(cnt, bsum);
    scan2_kernel<<<1, 64, 0, stream>>>(bsum, NB);
    scan3_kernel<<<NB, 256, 0, stream>>>(cnt, bsum, offs);
    partB2_kernel<<<NBUCKET, 256, 0, stream>>>(eb_dst, eb_src, bb, offs, dinv, csrc, cw);

    const int GEMM_BLOCKS = (NN + 63) / 64;
    const int AGG_BLOCKS = (NN + 15) / 16;
    // layer 0
    gemm_mfma_kernel<<<GEMM_BLOCKS, 256, 0, stream>>>(xb, Wpack, t8, NN);
    agg_relu_kernel<<<AGG_BLOCKS, 256, 0, stream>>>(t8, offs, csrc, cw, selfn, bc, bufH);
    // layer 1
    gemm_mfma_kernel<<<GEMM_BLOCKS, 256, 0, stream>>>(bufH, Wpack + 16384, t8, NN);
    agg_relu_kernel<<<AGG_BLOCKS, 256, 0, stream>>>(t8, offs, csrc, cw, selfn, bc + HH, bufH);
    // layer 2
    gemm_mfma_kernel<<<GEMM_BLOCKS, 256, 0, stream>>>(bufH, Wpack + 2 * 16384, t8, NN);
    agg_relu_kernel<<<AGG_BLOCKS, 256, 0, stream>>>(t8, offs, csrc, cw, selfn, bc + 2 * HH, bufH);

    // pooling + readout
    poolsum2_kernel<<<GG * 4, 256, 0, stream>>>(bufH, bat, psum, pcnt);
    mlp_kernel<<<GG, 128, 0, stream>>>(psum, pcnt, Wl1, bl1, Wl2, bl2, out);
}

// Round 10
// 290.575 us; speedup vs baseline: 1.8848x; 1.1208x over previous
//
#include <hip/hip_runtime.h>
#include <hip/hip_bf16.h>
#include <hip/hip_fp8.h>

#define NN 100000
#define NE 1600000
#define FF 128
#define HH 128
#define CC 10
#define GG 64

#define NCHUNK 2048
#define CE 782            // ceil(NE/NCHUNK)
#define NBUCKET 128
#define BSPAN 782         // ceil(NN/NBUCKET)

typedef __attribute__((ext_vector_type(8))) short short8;
typedef __attribute__((ext_vector_type(8))) unsigned short ushort8;
typedef __attribute__((ext_vector_type(4))) float f32x4;
typedef __attribute__((ext_vector_type(2))) float f32x2;

__device__ inline float bf2f(unsigned short u) {
    union { unsigned int i; float f; } x;
    x.i = ((unsigned int)u) << 16;
    return x.f;
}
__device__ inline unsigned short f2bf(float f) {
    union { float f; unsigned int i; } x;
    x.f = f;
    unsigned int r = x.i + 0x7FFF + ((x.i >> 16) & 1);  // RNE
    return (unsigned short)(r >> 16);
}
__device__ inline unsigned char f8enc(float v) {
    __hip_fp8_e4m3 q(v);
    return (unsigned char)q.__x;
}
__device__ inline float f8dec(unsigned char b) {
    __hip_fp8_e4m3 q;
    q.__x = (__hip_fp8_storage_t)b;
    return (float)q;
}

#if defined(__has_builtin)
#if __has_builtin(__builtin_amdgcn_cvt_pk_f32_fp8)
#define HAVE_CVT_PK_F32_FP8 1
#endif
#endif

// decode 8 fp8 (uint2) -> 8 f32
__device__ inline void dec8(uint2 v, float* o) {
#ifdef HAVE_CVT_PK_F32_FP8
    f32x2 p;
    p = __builtin_amdgcn_cvt_pk_f32_fp8(v.x, false); o[0] = p[0]; o[1] = p[1];
    p = __builtin_amdgcn_cvt_pk_f32_fp8(v.x, true);  o[2] = p[0]; o[3] = p[1];
    p = __builtin_amdgcn_cvt_pk_f32_fp8(v.y, false); o[4] = p[0]; o[5] = p[1];
    p = __builtin_amdgcn_cvt_pk_f32_fp8(v.y, true);  o[6] = p[0]; o[7] = p[1];
#else
#pragma unroll
    for (int j = 0; j < 4; ++j) {
        o[j]     = f8dec((v.x >> (8 * j)) & 0xFF);
        o[j + 4] = f8dec((v.y >> (8 * j)) & 0xFF);
    }
#endif
}

// ---------------- f32 -> bf16 bulk convert ----------------
__global__ __launch_bounds__(256) void f2bf_kernel(const float* __restrict__ x,
                                                   unsigned short* __restrict__ xb) {
    int i = blockIdx.x * blockDim.x + threadIdx.x;
    if (i >= NN * HH / 8) return;
    float4 v0 = ((const float4*)x)[i * 2];
    float4 v1 = ((const float4*)x)[i * 2 + 1];
    ushort8 o;
    o[0] = f2bf(v0.x); o[1] = f2bf(v0.y); o[2] = f2bf(v0.z); o[3] = f2bf(v0.w);
    o[4] = f2bf(v1.x); o[5] = f2bf(v1.y); o[6] = f2bf(v1.z); o[7] = f2bf(v1.w);
    ((ushort8*)xb)[i] = o;
}

// ---------------- weight combine + pack into MFMA B-fragment order ----------------
__global__ void combw_kernel(const float* __restrict__ W1, const float* __restrict__ b1,
                             const float* __restrict__ Wr1, const float* __restrict__ br1,
                             const float* __restrict__ W2, const float* __restrict__ b2,
                             const float* __restrict__ Wr, const float* __restrict__ br,
                             unsigned short* __restrict__ Wpack, float* __restrict__ bc) {
    int idx = blockIdx.x * blockDim.x + threadIdx.x;
    if (idx >= 3 * 16384) return;
    int l = idx / 16384, rem = idx % 16384;
    int cb = rem / 2048;
    int kb = (rem / 512) % 4;
    int lane = (rem / 8) % 64;
    int j = rem % 8;
    int k = kb * 32 + (lane >> 4) * 8 + j;
    int c = cb * 16 + (lane & 15);
    int wi = k * HH + c;
    float v = (l == 0) ? 0.95f * W1[wi] + 0.05f * Wr1[wi]
                       : 0.95f * W2[(l - 1) * 16384 + wi] + 0.05f * Wr[wi];
    Wpack[idx] = f2bf(v);
    if (rem < HH) {
        bc[l * HH + rem] = (l == 0) ? 0.95f * b1[rem] + 0.05f * br1[rem]
                                    : 0.95f * b2[(l - 1) * HH + rem] + 0.05f * br[rem];
    }
}

// ============ Phase A: deterministic edge partition by dst bucket ============
__global__ __launch_bounds__(256) void partA1_kernel(const int* __restrict__ ei,
                                                     int* __restrict__ cc) {
    __shared__ int h[NBUCKET];
    int c = blockIdx.x, t = threadIdx.x;
    if (t < NBUCKET) h[t] = 0;
    __syncthreads();
    int beg = c * CE, end = min(beg + CE, NE);
    for (int e = beg + t; e < end; e += 256) {
        int d = ei[NE + e];
        atomicAdd(&h[d / BSPAN], 1);
    }
    __syncthreads();
    if (t < NBUCKET) cc[c * NBUCKET + t] = h[t];
}

__global__ __launch_bounds__(256) void partA2_kernel(int* __restrict__ cc,
                                                     int* __restrict__ tot) {
    __shared__ int sh[256];
    int b = blockIdx.x, t = threadIdx.x;
    int v[8]; int s = 0;
#pragma unroll
    for (int i = 0; i < 8; ++i) { v[i] = cc[(t * 8 + i) * NBUCKET + b]; s += v[i]; }
    sh[t] = s; __syncthreads();
    for (int off = 1; off < 256; off <<= 1) {
        int x = (t >= off) ? sh[t - off] : 0; __syncthreads();
        sh[t] += x; __syncthreads();
    }
    int excl = sh[t] - s;
#pragma unroll
    for (int i = 0; i < 8; ++i) {
        cc[(t * 8 + i) * NBUCKET + b] = excl;
        excl += v[i];
    }
    if (t == 255) tot[b] = sh[255];
}

__global__ void scanB_kernel(const int* __restrict__ tot, int* __restrict__ bb) {
    if (threadIdx.x == 0 && blockIdx.x == 0) {
        int run = 0;
        for (int b = 0; b < NBUCKET; ++b) { bb[b] = run; run += tot[b]; }
        bb[NBUCKET] = run;
    }
}

__global__ __launch_bounds__(256) void partA3_kernel(const int* __restrict__ ei,
                                                     const int* __restrict__ cc,
                                                     const int* __restrict__ bb,
                                                     int* __restrict__ eb_dst,
                                                     int* __restrict__ eb_src) {
    __shared__ int cur[NBUCKET];
    int c = blockIdx.x, t = threadIdx.x;
    if (t < NBUCKET) cur[t] = bb[t] + cc[c * NBUCKET + t];
    __syncthreads();
    int beg = c * CE, end = min(beg + CE, NE);
    for (int e = beg + t; e < end; e += 256) {
        int d = ei[NE + e];
        int s = ei[e];
        int p = atomicAdd(&cur[d / BSPAN], 1);
        eb_dst[p] = d;
        eb_src[p] = s;
    }
}

__global__ __launch_bounds__(256) void partB1_kernel(const int* __restrict__ eb_dst,
                                                     const int* __restrict__ bb,
                                                     int* __restrict__ cnt) {
    __shared__ int h[BSPAN];
    int b = blockIdx.x, t = threadIdx.x;
    int lo = b * BSPAN;
    int span = min(BSPAN, NN - lo);
    if (span <= 0) return;
    for (int i = t; i < span; i += 256) h[i] = 0;
    __syncthreads();
    int beg = bb[b], end = bb[b + 1];
    for (int e = beg + t; e < end; e += 256)
        atomicAdd(&h[eb_dst[e] - lo], 1);
    __syncthreads();
    for (int i = t; i < span; i += 256) cnt[lo + i] = h[i];
}

__global__ void deg_kernel(const int* __restrict__ cnt, float* __restrict__ dinv) {
    int stride = gridDim.x * blockDim.x;
    for (int n = blockIdx.x * blockDim.x + threadIdx.x; n < NN; n += stride) {
        float dg = (float)cnt[n] + 1.0f;
        dinv[n] = rsqrtf(dg);
    }
}

// ---------------- 3-kernel exclusive scan of cnt -> offs ----------------
__global__ __launch_bounds__(256) void scan1_kernel(const int* __restrict__ cnt, int* __restrict__ bsum) {
    __shared__ int sh[256];
    int b = blockIdx.x, t = threadIdx.x;
    int base = b * 1024 + t * 4;
    int s = 0;
#pragma unroll
    for (int j = 0; j < 4; ++j) { int i = base + j; if (i < NN) s += cnt[i]; }
    sh[t] = s; __syncthreads();
    for (int off = 128; off; off >>= 1) { if (t < off) sh[t] += sh[t + off]; __syncthreads(); }
    if (t == 0) bsum[b] = sh[0];
}

__global__ void scan2_kernel(int* __restrict__ bsum, int nb) {
    if (threadIdx.x == 0 && blockIdx.x == 0) {
        int run = 0;
        for (int i = 0; i < nb; ++i) { int v = bsum[i]; bsum[i] = run; run += v; }
    }
}

__global__ __launch_bounds__(256) void scan3_kernel(const int* __restrict__ cnt, const int* __restrict__ bsum,
                                                    int* __restrict__ offs) {
    __shared__ int sh[256];
    int b = blockIdx.x, t = threadIdx.x;
    int base = b * 1024 + t * 4;
    int v[4]; int s = 0;
#pragma unroll
    for (int j = 0; j < 4; ++j) { int i = base + j; v[j] = (i < NN) ? cnt[i] : 0; s += v[j]; }
    sh[t] = s; __syncthreads();
    for (int off = 1; off < 256; off <<= 1) {
        int x = (t >= off) ? sh[t - off] : 0; __syncthreads();
        sh[t] += x; __syncthreads();
    }
    int excl = sh[t] - s + bsum[b];
#pragma unroll
    for (int j = 0; j < 4; ++j) {
        int i = base + j;
        if (i < NN) { offs[i] = excl; excl += v[j]; }
    }
    if (b == 0 && t == 0) offs[NN] = NE;
}

// B2: final CSR fill (src only) from bucketed edges; LDS cursors.
__global__ __launch_bounds__(256) void partB2_kernel(const int* __restrict__ eb_dst,
                                                     const int* __restrict__ eb_src,
                                                     const int* __restrict__ bb,
                                                     const int* __restrict__ offs,
                                                     int* __restrict__ csrc) {
    __shared__ int lcur[BSPAN];
    int b = blockIdx.x, t = threadIdx.x;
    int lo = b * BSPAN;
    int span = min(BSPAN, NN - lo);
    if (span <= 0) return;
    for (int i = t; i < span; i += 256) lcur[i] = offs[lo + i];
    __syncthreads();
    int beg = bb[b], end = bb[b + 1];
    for (int e = beg + t; e < end; e += 256) {
        int d = eb_dst[e] - lo;
        int s = eb_src[e];
        int p = atomicAdd(&lcur[d], 1);
        csrc[p] = s;
    }
}

// ------- MFMA GEMM: t8[N,128](fp8) = rowscale(dinv) * (A[N,128](bf16) @ Wc) -------
__global__ __launch_bounds__(256) void gemm_mfma_kernel(const unsigned short* __restrict__ A,
                                                        const unsigned short* __restrict__ Wp,
                                                        const float* __restrict__ dinv,
                                                        unsigned char* __restrict__ out8,
                                                        int nrows) {
    __shared__ unsigned char f8s[64][128];
    int w = threadIdx.x >> 6;
    int l = threadIdx.x & 63;
    int m0 = blockIdx.x * 64 + w * 16;
    int kg = l >> 4;
    int cl = l & 15;
    int arow = m0 + cl;

    short8 a[4];
    if (arow < nrows) {
        const short8* Ar = (const short8*)(A + (size_t)arow * HH);
#pragma unroll
        for (int kb = 0; kb < 4; ++kb) a[kb] = Ar[kb * 4 + kg];
    } else {
        short8 z = {};
#pragma unroll
        for (int kb = 0; kb < 4; ++kb) a[kb] = z;
    }

    // per-thread output rows are m0+kg*4+r; hoist their dinv
    float dv[4];
#pragma unroll
    for (int r = 0; r < 4; ++r) {
        int orow = m0 + kg * 4 + r;
        dv[r] = (orow < nrows) ? dinv[orow] : 0.f;
    }

#pragma unroll
    for (int cb = 0; cb < 8; ++cb) {
        f32x4 acc = {0.f, 0.f, 0.f, 0.f};
#pragma unroll
        for (int kb = 0; kb < 4; ++kb) {
            short8 b = *(const short8*)(Wp + (size_t)(cb * 4 + kb) * 512 + l * 8);
            acc = __builtin_amdgcn_mfma_f32_16x16x32_bf16(a[kb], b, acc, 0, 0, 0);
        }
#pragma unroll
        for (int r = 0; r < 4; ++r)
            f8s[w * 16 + kg * 4 + r][cb * 16 + cl] = f8enc(acc[r] * dv[r]);
    }
    __syncthreads();
    int blk0 = blockIdx.x * 64;
    for (int u = threadIdx.x; u < 512; u += 256) {       // 64 rows x 8 x 16B
        int row = u >> 3, c16 = u & 7;
        int grow = blk0 + row;
        if (grow < nrows)
            ((uint4*)out8)[(size_t)grow * 8 + c16] = ((const uint4*)&f8s[row][0])[c16];
    }
}

// ---- aggregation: out[n] = relu(dinv[n]*(t'[n] + sum_{s in N(n)} t'[s]) + b) ----
__global__ __launch_bounds__(256) void agg_relu_kernel(const unsigned char* __restrict__ t8,
                                                       const int* __restrict__ offs,
                                                       const int* __restrict__ csrc,
                                                       const float* __restrict__ dinv,
                                                       const float* __restrict__ bias,
                                                       unsigned short* __restrict__ hOut) {
    int n = blockIdx.x * 16 + (threadIdx.x >> 4);
    if (n >= NN) return;
    int lane = threadIdx.x & 15;          // features lane*8 .. lane*8+7
    int beg = offs[n], end = offs[n + 1];
    const uint2* g8 = (const uint2*)t8;   // row = 16 uint2 (128 fp8)
    float acc[8] = {};
    float d[8];
    int e = beg;
    for (; e + 3 < end; e += 4) {
        int s0 = csrc[e], s1 = csrc[e + 1], s2 = csrc[e + 2], s3 = csrc[e + 3];
        uint2 v0 = g8[(size_t)s0 * 16 + lane];
        uint2 v1 = g8[(size_t)s1 * 16 + lane];
        uint2 v2 = g8[(size_t)s2 * 16 + lane];
        uint2 v3 = g8[(size_t)s3 * 16 + lane];
        dec8(v0, d);
#pragma unroll
        for (int j = 0; j < 8; ++j) acc[j] += d[j];
        dec8(v1, d);
#pragma unroll
        for (int j = 0; j < 8; ++j) acc[j] += d[j];
        dec8(v2, d);
#pragma unroll
        for (int j = 0; j < 8; ++j) acc[j] += d[j];
        dec8(v3, d);
#pragma unroll
        for (int j = 0; j < 8; ++j) acc[j] += d[j];
    }
    for (; e < end; ++e) {
        uint2 v = g8[(size_t)csrc[e] * 16 + lane];
        dec8(v, d);
#pragma unroll
        for (int j = 0; j < 8; ++j) acc[j] += d[j];
    }
    // self term: + t'[n]
    {
        uint2 v = g8[(size_t)n * 16 + lane];
        dec8(v, d);
#pragma unroll
        for (int j = 0; j < 8; ++j) acc[j] += d[j];
    }
    float dn = dinv[n];
    float4 bv0 = ((const float4*)bias)[lane * 2];
    float4 bv1 = ((const float4*)bias)[lane * 2 + 1];
    float bb[8] = {bv0.x, bv0.y, bv0.z, bv0.w, bv1.x, bv1.y, bv1.z, bv1.w};
    ushort8 o;
#pragma unroll
    for (int j = 0; j < 8; ++j) {
        float v = fmaxf(fmaf(acc[j], dn, bb[j]), 0.f);
        o[j] = f2bf(v);
    }
    ((ushort8*)hOut)[(size_t)n * 16 + lane] = o;
}

// -------- pooling: 4 segments/graph, vectorized, LDS reduce, few atomics --------
__global__ __launch_bounds__(256) void poolsum2_kernel(const unsigned short* __restrict__ h,
                                                       const int* __restrict__ batch,
                                                       float* __restrict__ psum,
                                                       int* __restrict__ pcnt) {
    int g = blockIdx.x >> 2;
    int seg = blockIdx.x & 3;
    int t = threadIdx.x;
    int lo = 0, hi = NN;
    while (lo < hi) { int m = (lo + hi) >> 1; if (batch[m] < g) lo = m + 1; else hi = m; }
    int lb = lo;
    lo = 0; hi = NN;
    while (lo < hi) { int m = (lo + hi) >> 1; if (batch[m] <= g) lo = m + 1; else hi = m; }
    int ub = lo;
    int len = ub - lb;
    if (seg == 0 && t == 0) pcnt[g] = len;
    int b0 = lb + (int)(((long long)len * seg) / 4);
    int b1 = lb + (int)(((long long)len * (seg + 1)) / 4);

    int fg = t & 15;
    int rg = t >> 4;
    const ushort8* h8 = (const ushort8*)h;
    float acc[8] = {};
    for (int n = b0 + rg; n < b1; n += 16) {
        ushort8 v = h8[(size_t)n * 16 + fg];
#pragma unroll
        for (int j = 0; j < 8; ++j) acc[j] += bf2f(v[j]);
    }
    __shared__ float red[256][8];
#pragma unroll
    for (int j = 0; j < 8; ++j) red[t][j] = acc[j];
    __syncthreads();
    for (int off = 128; off >= 16; off >>= 1) {
        if (t < off) {
#pragma unroll
            for (int j = 0; j < 8; ++j) red[t][j] += red[t + off][j];
        }
        __syncthreads();
    }
    if (t < 16) {
#pragma unroll
        for (int j = 0; j < 8; ++j)
            atomicAdd(&psum[g * HH + t * 8 + j], red[t][j]);
    }
}

// ---------------- readout MLP + log_softmax ----------------
__global__ __launch_bounds__(128) void mlp_kernel(const float* __restrict__ psum,
                                                  const int* __restrict__ pcnt,
                                                  const float* __restrict__ Wl1,
                                                  const float* __restrict__ bl1,
                                                  const float* __restrict__ Wl2,
                                                  const float* __restrict__ bl2,
                                                  float* __restrict__ out) {
    __shared__ float p[128], o1[128], lg[CC];
    int g = blockIdx.x, t = threadIdx.x;
    float cnt = fmaxf((float)pcnt[g], 1.0f);
    p[t] = psum[g * HH + t] / cnt;
    __syncthreads();
    float acc = bl1[t];
    for (int k = 0; k < HH; ++k) acc = fmaf(p[k], Wl1[k * HH + t], acc);
    o1[t] = fmaxf(acc, 0.f);
    __syncthreads();
    if (t < CC) {
        float a2 = bl2[t];
        for (int j = 0; j < HH; ++j) a2 = fmaf(o1[j], Wl2[j * CC + t], a2);
        lg[t] = a2;
    }
    __syncthreads();
    if (t == 0) {
        float m = lg[0];
        for (int c = 1; c < CC; ++c) m = fmaxf(m, lg[c]);
        float s = 0.f;
        for (int c = 0; c < CC; ++c) s += expf(lg[c] - m);
        float ls = logf(s);
        for (int c = 0; c < CC; ++c) out[g * CC + c] = lg[c] - m - ls;
    }
}

extern "C" void kernel_launch(void* const* d_in, const int* in_sizes, int n_in,
                              void* d_out, int out_size, void* d_ws, size_t ws_size,
                              hipStream_t stream) {
    const float* x   = (const float*)d_in[0];
    const int*   ei  = (const int*)d_in[1];
    const int*   bat = (const int*)d_in[2];
    const float* W1  = (const float*)d_in[3];
    const float* b1  = (const float*)d_in[4];
    const float* Wr1 = (const float*)d_in[5];
    const float* br1 = (const float*)d_in[6];
    const float* W2  = (const float*)d_in[7];
    const float* b2  = (const float*)d_in[8];
    const float* Wr  = (const float*)d_in[9];
    const float* br  = (const float*)d_in[10];
    const float* Wl1 = (const float*)d_in[11];
    const float* bl1 = (const float*)d_in[12];
    const float* Wl2 = (const float*)d_in[13];
    const float* bl2 = (const float*)d_in[14];
    float* out = (float*)d_out;

    // workspace carve-up (256B aligned)
    char* base = (char*)d_ws;
    size_t off = 0;
    auto alloc = [&](size_t bytes) {
        void* p = base + off;
        off += (bytes + 255) & ~(size_t)255;
        return p;
    };
    unsigned short* xb   = (unsigned short*)alloc((size_t)NN * HH * 2);
    unsigned short* bufH = (unsigned short*)alloc((size_t)NN * HH * 2);
    unsigned char*  t8   = (unsigned char*)alloc((size_t)NN * HH);
    int*   csrc   = (int*)alloc((size_t)NE * 4);
    int*   offs   = (int*)alloc((size_t)(NN + 1) * 4);
    int*   cnt    = (int*)alloc((size_t)NN * 4);
    float* dinv   = (float*)alloc((size_t)NN * 4);
    int*   bsum   = (int*)alloc(128 * 4);
    unsigned short* Wpack = (unsigned short*)alloc(3 * 16384 * 2);
    float* bc     = (float*)alloc(3 * HH * 4);
    float* psum   = (float*)alloc(GG * HH * 4);
    int*   pcnt   = (int*)alloc(GG * 4);
    int*   tot    = (int*)alloc(NBUCKET * 4);
    int*   bb     = (int*)alloc((NBUCKET + 1) * 4);
    // partition scratch aliases into bufH (dead until agg layer 0 writes it)
    int* eb_dst = (int*)bufH;                  // 6.4 MB
    int* eb_src = (int*)bufH + NE;             // 6.4 MB
    int* cc     = (int*)bufH + 2 * NE;         // 1 MB (bufH = 25.6 MB total)
    (void)ws_size; (void)in_sizes; (void)n_in; (void)out_size;

    hipMemsetAsync(psum, 0, (size_t)GG * HH * 4, stream);

    // input convert + combined packed weights
    f2bf_kernel<<<(NN * HH / 8 + 255) / 256, 256, 0, stream>>>(x, xb);
    combw_kernel<<<(3 * 16384 + 255) / 256, 256, 0, stream>>>(W1, b1, Wr1, br1, W2, b2, Wr, br, Wpack, bc);

    // deterministic two-phase partition
    partA1_kernel<<<NCHUNK, 256, 0, stream>>>(ei, cc);
    partA2_kernel<<<NBUCKET, 256, 0, stream>>>(cc, tot);
    scanB_kernel<<<1, 64, 0, stream>>>(tot, bb);
    partA3_kernel<<<NCHUNK, 256, 0, stream>>>(ei, cc, bb, eb_dst, eb_src);
    partB1_kernel<<<NBUCKET, 256, 0, stream>>>(eb_dst, bb, cnt);
    deg_kernel<<<512, 256, 0, stream>>>(cnt, dinv);
    const int NB = (NN + 1023) / 1024;  // 98
    scan1_kernel<<<NB, 256, 0, stream>>>(cnt, bsum);
    scan2_kernel<<<1, 64, 0, stream>>>(bsum, NB);
    scan3_kernel<<<NB, 256, 0, stream>>>(cnt, bsum, offs);
    partB2_kernel<<<NBUCKET, 256, 0, stream>>>(eb_dst, eb_src, bb, offs, csrc);

    const int GEMM_BLOCKS = (NN + 63) / 64;
    const int AGG_BLOCKS = (NN + 15) / 16;
    // layer 0
    gemm_mfma_kernel<<<GEMM_BLOCKS, 256, 0, stream>>>(xb, Wpack, dinv, t8, NN);
    agg_relu_kernel<<<AGG_BLOCKS, 256, 0, stream>>>(t8, offs, csrc, dinv, bc, bufH);
    // layer 1
    gemm_mfma_kernel<<<GEMM_BLOCKS, 256, 0, stream>>>(bufH, Wpack + 16384, dinv, t8, NN);
    agg_relu_kernel<<<AGG_BLOCKS, 256, 0, stream>>>(t8, offs, csrc, dinv, bc + HH, bufH);
    // layer 2
    gemm_mfma_kernel<<<GEMM_BLOCKS, 256, 0, stream>>>(bufH, Wpack + 2 * 16384, dinv, t8, NN);
    agg_relu_kernel<<<AGG_BLOCKS, 256, 0, stream>>>(t8, offs, csrc, dinv, bc + 2 * HH, bufH);

    // pooling + readout
    poolsum2_kernel<<<GG * 4, 256, 0, stream>>>(bufH, bat, psum, pcnt);
    mlp_kernel<<<GG, 128, 0, stream>>>(psum, pcnt, Wl1, bl1, Wl2, bl2, out);
}

// Round 11
// 286.956 us; speedup vs baseline: 1.9086x; 1.0126x over previous
//
#include <hip/hip_runtime.h>
#include <hip/hip_bf16.h>
#include <hip/hip_fp8.h>

#define NN 100000
#define NE 1600000
#define FF 128
#define HH 128
#define CC 10
#define GG 64

#define NCHUNK 2048
#define CE 782            // ceil(NE/NCHUNK)
#define NBUCKET 128
#define BSPAN 782         // ceil(NN/NBUCKET)
#define XCONV_BLOCKS 6250 // NN*HH/8/256

typedef __attribute__((ext_vector_type(8))) short short8;
typedef __attribute__((ext_vector_type(8))) unsigned short ushort8;
typedef __attribute__((ext_vector_type(4))) float f32x4;
typedef __attribute__((ext_vector_type(2))) float f32x2;

__device__ inline float bf2f(unsigned short u) {
    union { unsigned int i; float f; } x;
    x.i = ((unsigned int)u) << 16;
    return x.f;
}
__device__ inline unsigned short f2bf(float f) {
    union { float f; unsigned int i; } x;
    x.f = f;
    unsigned int r = x.i + 0x7FFF + ((x.i >> 16) & 1);  // RNE
    return (unsigned short)(r >> 16);
}
__device__ inline unsigned char f8enc(float v) {
    __hip_fp8_e4m3 q(v);
    return (unsigned char)q.__x;
}
__device__ inline float f8dec(unsigned char b) {
    __hip_fp8_e4m3 q;
    q.__x = (__hip_fp8_storage_t)b;
    return (float)q;
}

#if defined(__has_builtin)
#if __has_builtin(__builtin_amdgcn_cvt_pk_f32_fp8)
#define HAVE_CVT_PK_F32_FP8 1
#endif
#endif

// decode 8 fp8 (uint2) -> 8 f32
__device__ inline void dec8(uint2 v, float* o) {
#ifdef HAVE_CVT_PK_F32_FP8
    f32x2 p;
    p = __builtin_amdgcn_cvt_pk_f32_fp8(v.x, false); o[0] = p[0]; o[1] = p[1];
    p = __builtin_amdgcn_cvt_pk_f32_fp8(v.x, true);  o[2] = p[0]; o[3] = p[1];
    p = __builtin_amdgcn_cvt_pk_f32_fp8(v.y, false); o[4] = p[0]; o[5] = p[1];
    p = __builtin_amdgcn_cvt_pk_f32_fp8(v.y, true);  o[6] = p[0]; o[7] = p[1];
#else
#pragma unroll
    for (int j = 0; j < 4; ++j) {
        o[j]     = f8dec((v.x >> (8 * j)) & 0xFF);
        o[j + 4] = f8dec((v.y >> (8 * j)) & 0xFF);
    }
#endif
}
// encode 8 f32 -> uint2 of fp8
__device__ inline uint2 enc8(const float* d) {
    unsigned a = 0, b = 0;
#pragma unroll
    for (int j = 0; j < 4; ++j) {
        a |= ((unsigned)f8enc(d[j])) << (8 * j);
        b |= ((unsigned)f8enc(d[j + 4])) << (8 * j);
    }
    uint2 o; o.x = a; o.y = b; return o;
}

// -------- fused: x f32 -> fp8 convert (blocks < XCONV_BLOCKS) + weight combine/pack --------
__global__ __launch_bounds__(256) void combo_kernel(const float* __restrict__ x,
                                                    unsigned char* __restrict__ x8,
                                                    const float* __restrict__ W1, const float* __restrict__ b1,
                                                    const float* __restrict__ Wr1, const float* __restrict__ br1,
                                                    const float* __restrict__ W2, const float* __restrict__ b2,
                                                    const float* __restrict__ Wr, const float* __restrict__ br,
                                                    unsigned short* __restrict__ Wpack, float* __restrict__ bc) {
    int bid = blockIdx.x;
    if (bid < XCONV_BLOCKS) {
        int i = bid * 256 + threadIdx.x;      // 8-elem group
        float4 v0 = ((const float4*)x)[i * 2];
        float4 v1 = ((const float4*)x)[i * 2 + 1];
        float d[8] = {v0.x, v0.y, v0.z, v0.w, v1.x, v1.y, v1.z, v1.w};
        ((uint2*)x8)[i] = enc8(d);
        return;
    }
    int idx = (bid - XCONV_BLOCKS) * 256 + threadIdx.x;   // < 3*16384
    int l = idx / 16384, rem = idx % 16384;
    int cb = rem / 2048;
    int kb = (rem / 512) % 4;
    int lane = (rem / 8) % 64;
    int j = rem % 8;
    int k = kb * 32 + (lane >> 4) * 8 + j;
    int c = cb * 16 + (lane & 15);
    int wi = k * HH + c;
    float v = (l == 0) ? 0.95f * W1[wi] + 0.05f * Wr1[wi]
                       : 0.95f * W2[(l - 1) * 16384 + wi] + 0.05f * Wr[wi];
    Wpack[idx] = f2bf(v);
    if (rem < HH) {
        bc[l * HH + rem] = (l == 0) ? 0.95f * b1[rem] + 0.05f * br1[rem]
                                    : 0.95f * b2[(l - 1) * HH + rem] + 0.05f * br[rem];
    }
}

// ============ Phase A: deterministic edge partition by dst bucket ============
__global__ __launch_bounds__(256) void partA1_kernel(const int* __restrict__ ei,
                                                     int* __restrict__ cc) {
    __shared__ int h[NBUCKET];
    int c = blockIdx.x, t = threadIdx.x;
    if (t < NBUCKET) h[t] = 0;
    __syncthreads();
    int beg = c * CE, end = min(beg + CE, NE);
    for (int e = beg + t; e < end; e += 256) {
        int d = ei[NE + e];
        atomicAdd(&h[d / BSPAN], 1);
    }
    __syncthreads();
    if (t < NBUCKET) cc[c * NBUCKET + t] = h[t];
}

__global__ __launch_bounds__(256) void partA2_kernel(int* __restrict__ cc,
                                                     int* __restrict__ tot) {
    __shared__ int sh[256];
    int b = blockIdx.x, t = threadIdx.x;
    int v[8]; int s = 0;
#pragma unroll
    for (int i = 0; i < 8; ++i) { v[i] = cc[(t * 8 + i) * NBUCKET + b]; s += v[i]; }
    sh[t] = s; __syncthreads();
    for (int off = 1; off < 256; off <<= 1) {
        int x = (t >= off) ? sh[t - off] : 0; __syncthreads();
        sh[t] += x; __syncthreads();
    }
    int excl = sh[t] - s;
#pragma unroll
    for (int i = 0; i < 8; ++i) {
        cc[(t * 8 + i) * NBUCKET + b] = excl;
        excl += v[i];
    }
    if (t == 255) tot[b] = sh[255];
}

__global__ void scanB_kernel(const int* __restrict__ tot, int* __restrict__ bb) {
    if (threadIdx.x == 0 && blockIdx.x == 0) {
        int run = 0;
        for (int b = 0; b < NBUCKET; ++b) { bb[b] = run; run += tot[b]; }
        bb[NBUCKET] = run;
    }
}

// A3: scatter packed (dst,src) pairs into bucket-partitioned array via LDS cursors
__global__ __launch_bounds__(256) void partA3_kernel(const int* __restrict__ ei,
                                                     const int* __restrict__ cc,
                                                     const int* __restrict__ bb,
                                                     uint2* __restrict__ eb) {
    __shared__ int cur[NBUCKET];
    int c = blockIdx.x, t = threadIdx.x;
    if (t < NBUCKET) cur[t] = bb[t] + cc[c * NBUCKET + t];
    __syncthreads();
    int beg = c * CE, end = min(beg + CE, NE);
    for (int e = beg + t; e < end; e += 256) {
        int d = ei[NE + e];
        int s = ei[e];
        int p = atomicAdd(&cur[d / BSPAN], 1);
        uint2 pr; pr.x = (unsigned)d; pr.y = (unsigned)s;
        eb[p] = pr;
    }
}

__global__ __launch_bounds__(256) void partB1_kernel(const uint2* __restrict__ eb,
                                                     const int* __restrict__ bb,
                                                     int* __restrict__ cnt) {
    __shared__ int h[BSPAN];
    int b = blockIdx.x, t = threadIdx.x;
    int lo = b * BSPAN;
    int span = min(BSPAN, NN - lo);
    if (span <= 0) return;
    for (int i = t; i < span; i += 256) h[i] = 0;
    __syncthreads();
    int beg = bb[b], end = bb[b + 1];
    for (int e = beg + t; e < end; e += 256)
        atomicAdd(&h[eb[e].x - lo], 1);
    __syncthreads();
    for (int i = t; i < span; i += 256) cnt[lo + i] = h[i];
}

// ---------------- scan of cnt -> offs (+ dinv folded into scan3) ----------------
__global__ __launch_bounds__(256) void scan1_kernel(const int* __restrict__ cnt, int* __restrict__ bsum) {
    __shared__ int sh[256];
    int b = blockIdx.x, t = threadIdx.x;
    int base = b * 1024 + t * 4;
    int s = 0;
#pragma unroll
    for (int j = 0; j < 4; ++j) { int i = base + j; if (i < NN) s += cnt[i]; }
    sh[t] = s; __syncthreads();
    for (int off = 128; off; off >>= 1) { if (t < off) sh[t] += sh[t + off]; __syncthreads(); }
    if (t == 0) bsum[b] = sh[0];
}

__global__ void scan2_kernel(int* __restrict__ bsum, int nb) {
    if (threadIdx.x == 0 && blockIdx.x == 0) {
        int run = 0;
        for (int i = 0; i < nb; ++i) { int v = bsum[i]; bsum[i] = run; run += v; }
    }
}

__global__ __launch_bounds__(256) void scan3_kernel(const int* __restrict__ cnt, const int* __restrict__ bsum,
                                                    int* __restrict__ offs, float* __restrict__ dinv) {
    __shared__ int sh[256];
    int b = blockIdx.x, t = threadIdx.x;
    int base = b * 1024 + t * 4;
    int v[4]; int s = 0;
#pragma unroll
    for (int j = 0; j < 4; ++j) { int i = base + j; v[j] = (i < NN) ? cnt[i] : 0; s += v[j]; }
    sh[t] = s; __syncthreads();
    for (int off = 1; off < 256; off <<= 1) {
        int x = (t >= off) ? sh[t - off] : 0; __syncthreads();
        sh[t] += x; __syncthreads();
    }
    int excl = sh[t] - s + bsum[b];
#pragma unroll
    for (int j = 0; j < 4; ++j) {
        int i = base + j;
        if (i < NN) {
            offs[i] = excl; excl += v[j];
            dinv[i] = rsqrtf((float)v[j] + 1.0f);
        }
    }
    if (b == 0 && t == 0) offs[NN] = NE;
}

// B2: final CSR fill (src only) from bucketed edges; LDS cursors.
__global__ __launch_bounds__(256) void partB2_kernel(const uint2* __restrict__ eb,
                                                     const int* __restrict__ bb,
                                                     const int* __restrict__ offs,
                                                     int* __restrict__ csrc) {
    __shared__ int lcur[BSPAN];
    int b = blockIdx.x, t = threadIdx.x;
    int lo = b * BSPAN;
    int span = min(BSPAN, NN - lo);
    if (span <= 0) return;
    for (int i = t; i < span; i += 256) lcur[i] = offs[lo + i];
    __syncthreads();
    int beg = bb[b], end = bb[b + 1];
    for (int e = beg + t; e < end; e += 256) {
        uint2 pr = eb[e];
        int p = atomicAdd(&lcur[pr.x - lo], 1);
        csrc[p] = (int)pr.y;
    }
}

// ------- MFMA GEMM: t8[N,128](fp8) = rowscale(dinv) * (A8[N,128](fp8->bf16) @ Wc) -------
__global__ __launch_bounds__(256) void gemm_mfma_kernel(const unsigned char* __restrict__ A8,
                                                        const unsigned short* __restrict__ Wp,
                                                        const float* __restrict__ dinv,
                                                        unsigned char* __restrict__ out8,
                                                        int nrows) {
    __shared__ unsigned char f8s[64][128];
    int w = threadIdx.x >> 6;
    int l = threadIdx.x & 63;
    int m0 = blockIdx.x * 64 + w * 16;
    int kg = l >> 4;
    int cl = l & 15;
    int arow = m0 + cl;

    short8 a[4];
    if (arow < nrows) {
        const uint2* Ar = (const uint2*)(A8 + (size_t)arow * HH);
#pragma unroll
        for (int kb = 0; kb < 4; ++kb) {
            uint2 v = Ar[kb * 4 + kg];
            float d[8]; dec8(v, d);
            short8 t;
#pragma unroll
            for (int j = 0; j < 8; ++j) t[j] = (short)f2bf(d[j]);
            a[kb] = t;
        }
    } else {
        short8 z = {};
#pragma unroll
        for (int kb = 0; kb < 4; ++kb) a[kb] = z;
    }

    float dv[4];
#pragma unroll
    for (int r = 0; r < 4; ++r) {
        int orow = m0 + kg * 4 + r;
        dv[r] = (orow < nrows) ? dinv[orow] : 0.f;
    }

#pragma unroll
    for (int cb = 0; cb < 8; ++cb) {
        f32x4 acc = {0.f, 0.f, 0.f, 0.f};
#pragma unroll
        for (int kb = 0; kb < 4; ++kb) {
            short8 b = *(const short8*)(Wp + (size_t)(cb * 4 + kb) * 512 + l * 8);
            acc = __builtin_amdgcn_mfma_f32_16x16x32_bf16(a[kb], b, acc, 0, 0, 0);
        }
#pragma unroll
        for (int r = 0; r < 4; ++r)
            f8s[w * 16 + kg * 4 + r][cb * 16 + cl] = f8enc(acc[r] * dv[r]);
    }
    __syncthreads();
    int blk0 = blockIdx.x * 64;
    for (int u = threadIdx.x; u < 512; u += 256) {       // 64 rows x 8 x 16B
        int row = u >> 3, c16 = u & 7;
        int grow = blk0 + row;
        if (grow < nrows)
            ((uint4*)out8)[(size_t)grow * 8 + c16] = ((const uint4*)&f8s[row][0])[c16];
    }
}

// ---- aggregation: h8[n] = fp8(relu(dinv[n]*(t'[n] + sum_{s} t'[s]) + b)) ----
__global__ __launch_bounds__(256) void agg_relu_kernel(const unsigned char* __restrict__ t8,
                                                       const int* __restrict__ offs,
                                                       const int* __restrict__ csrc,
                                                       const float* __restrict__ dinv,
                                                       const float* __restrict__ bias,
                                                       unsigned char* __restrict__ hOut) {
    int n = blockIdx.x * 16 + (threadIdx.x >> 4);
    if (n >= NN) return;
    int lane = threadIdx.x & 15;          // features lane*8 .. lane*8+7
    int beg = offs[n], end = offs[n + 1];
    const uint2* g8 = (const uint2*)t8;
    float acc[8] = {};
    float d[8];
    int e = beg;
    for (; e + 3 < end; e += 4) {
        int s0 = csrc[e], s1 = csrc[e + 1], s2 = csrc[e + 2], s3 = csrc[e + 3];
        uint2 v0 = g8[(size_t)s0 * 16 + lane];
        uint2 v1 = g8[(size_t)s1 * 16 + lane];
        uint2 v2 = g8[(size_t)s2 * 16 + lane];
        uint2 v3 = g8[(size_t)s3 * 16 + lane];
        dec8(v0, d);
#pragma unroll
        for (int j = 0; j < 8; ++j) acc[j] += d[j];
        dec8(v1, d);
#pragma unroll
        for (int j = 0; j < 8; ++j) acc[j] += d[j];
        dec8(v2, d);
#pragma unroll
        for (int j = 0; j < 8; ++j) acc[j] += d[j];
        dec8(v3, d);
#pragma unroll
        for (int j = 0; j < 8; ++j) acc[j] += d[j];
    }
    for (; e < end; ++e) {
        uint2 v = g8[(size_t)csrc[e] * 16 + lane];
        dec8(v, d);
#pragma unroll
        for (int j = 0; j < 8; ++j) acc[j] += d[j];
    }
    {   // self term
        uint2 v = g8[(size_t)n * 16 + lane];
        dec8(v, d);
#pragma unroll
        for (int j = 0; j < 8; ++j) acc[j] += d[j];
    }
    float dn = dinv[n];
    float4 bv0 = ((const float4*)bias)[lane * 2];
    float4 bv1 = ((const float4*)bias)[lane * 2 + 1];
    float bb[8] = {bv0.x, bv0.y, bv0.z, bv0.w, bv1.x, bv1.y, bv1.z, bv1.w};
    float o[8];
#pragma unroll
    for (int j = 0; j < 8; ++j) o[j] = fmaxf(fmaf(acc[j], dn, bb[j]), 0.f);
    ((uint2*)hOut)[(size_t)n * 16 + lane] = enc8(o);
}

// -------- fused pooling + readout MLP + log_softmax: one block per graph --------
__global__ __launch_bounds__(256) void pool_mlp_kernel(const unsigned char* __restrict__ h8,
                                                       const int* __restrict__ batch,
                                                       const float* __restrict__ Wl1,
                                                       const float* __restrict__ bl1,
                                                       const float* __restrict__ Wl2,
                                                       const float* __restrict__ bl2,
                                                       float* __restrict__ out) {
    int g = blockIdx.x, t = threadIdx.x;
    int lo = 0, hi = NN;
    while (lo < hi) { int m = (lo + hi) >> 1; if (batch[m] < g) lo = m + 1; else hi = m; }
    int lb = lo;
    lo = 0; hi = NN;
    while (lo < hi) { int m = (lo + hi) >> 1; if (batch[m] <= g) lo = m + 1; else hi = m; }
    int ub = lo;
    int len = ub - lb;

    int fg = t & 15;        // feature group
    int rg = t >> 4;        // row slot 0..15
    const uint2* gp = (const uint2*)h8;
    float acc[8] = {};
    for (int n = lb + rg; n < ub; n += 16) {
        uint2 v = gp[(size_t)n * 16 + fg];
        float d[8]; dec8(v, d);
#pragma unroll
        for (int j = 0; j < 8; ++j) acc[j] += d[j];
    }
    __shared__ float red[256][8];
#pragma unroll
    for (int j = 0; j < 8; ++j) red[t][j] = acc[j];
    __syncthreads();
    for (int off = 8; off >= 1; off >>= 1) {
        if (rg < off) {
#pragma unroll
            for (int j = 0; j < 8; ++j) red[t][j] += red[t + off * 16][j];
        }
        __syncthreads();
    }
    __shared__ float p[128], o1[128], lg[CC];
    float cscale = 1.f / fmaxf((float)len, 1.f);
    if (t < 16) {
#pragma unroll
        for (int j = 0; j < 8; ++j) p[t * 8 + j] = red[t][j] * cscale;
    }
    __syncthreads();
    if (t < 128) {
        float a = bl1[t];
        for (int k = 0; k < HH; ++k) a = fmaf(p[k], Wl1[k * HH + t], a);
        o1[t] = fmaxf(a, 0.f);
    }
    __syncthreads();
    if (t < CC) {
        float a2 = bl2[t];
        for (int j = 0; j < HH; ++j) a2 = fmaf(o1[j], Wl2[j * CC + t], a2);
        lg[t] = a2;
    }
    __syncthreads();
    if (t == 0) {
        float m = lg[0];
        for (int c = 1; c < CC; ++c) m = fmaxf(m, lg[c]);
        float s = 0.f;
        for (int c = 0; c < CC; ++c) s += expf(lg[c] - m);
        float ls = logf(s);
        for (int c = 0; c < CC; ++c) out[g * CC + c] = lg[c] - m - ls;
    }
}

extern "C" void kernel_launch(void* const* d_in, const int* in_sizes, int n_in,
                              void* d_out, int out_size, void* d_ws, size_t ws_size,
                              hipStream_t stream) {
    const float* x   = (const float*)d_in[0];
    const int*   ei  = (const int*)d_in[1];
    const int*   bat = (const int*)d_in[2];
    const float* W1  = (const float*)d_in[3];
    const float* b1  = (const float*)d_in[4];
    const float* Wr1 = (const float*)d_in[5];
    const float* br1 = (const float*)d_in[6];
    const float* W2  = (const float*)d_in[7];
    const float* b2  = (const float*)d_in[8];
    const float* Wr  = (const float*)d_in[9];
    const float* br  = (const float*)d_in[10];
    const float* Wl1 = (const float*)d_in[11];
    const float* bl1 = (const float*)d_in[12];
    const float* Wl2 = (const float*)d_in[13];
    const float* bl2 = (const float*)d_in[14];
    float* out = (float*)d_out;

    // workspace carve-up (256B aligned)
    char* base = (char*)d_ws;
    size_t off = 0;
    auto alloc = [&](size_t bytes) {
        void* p = base + off;
        off += (bytes + 255) & ~(size_t)255;
        return p;
    };
    unsigned char* x8   = (unsigned char*)alloc((size_t)NN * HH);
    unsigned char* h8   = (unsigned char*)alloc((size_t)NN * HH);
    unsigned char* t8   = (unsigned char*)alloc((size_t)NN * HH);
    uint2* eb     = (uint2*)alloc((size_t)NE * 8);
    int*   cc     = (int*)alloc((size_t)NCHUNK * NBUCKET * 4);
    int*   csrc   = (int*)alloc((size_t)NE * 4);
    int*   offs   = (int*)alloc((size_t)(NN + 1) * 4);
    int*   cnt    = (int*)alloc((size_t)NN * 4);
    float* dinv   = (float*)alloc((size_t)NN * 4);
    int*   bsum   = (int*)alloc(128 * 4);
    unsigned short* Wpack = (unsigned short*)alloc(3 * 16384 * 2);
    float* bc     = (float*)alloc(3 * HH * 4);
    int*   tot    = (int*)alloc(NBUCKET * 4);
    int*   bb     = (int*)alloc((NBUCKET + 1) * 4);
    (void)ws_size; (void)in_sizes; (void)n_in; (void)out_size;

    // fused input-convert + weight combine
    combo_kernel<<<XCONV_BLOCKS + 192, 256, 0, stream>>>(x, x8, W1, b1, Wr1, br1,
                                                         W2, b2, Wr, br, Wpack, bc);

    // deterministic two-phase partition
    partA1_kernel<<<NCHUNK, 256, 0, stream>>>(ei, cc);
    partA2_kernel<<<NBUCKET, 256, 0, stream>>>(cc, tot);
    scanB_kernel<<<1, 64, 0, stream>>>(tot, bb);
    partA3_kernel<<<NCHUNK, 256, 0, stream>>>(ei, cc, bb, eb);
    partB1_kernel<<<NBUCKET, 256, 0, stream>>>(eb, bb, cnt);
    const int NB = (NN + 1023) / 1024;  // 98
    scan1_kernel<<<NB, 256, 0, stream>>>(cnt, bsum);
    scan2_kernel<<<1, 64, 0, stream>>>(bsum, NB);
    scan3_kernel<<<NB, 256, 0, stream>>>(cnt, bsum, offs, dinv);
    partB2_kernel<<<NBUCKET, 256, 0, stream>>>(eb, bb, offs, csrc);

    const int GEMM_BLOCKS = (NN + 63) / 64;
    const int AGG_BLOCKS = (NN + 15) / 16;
    // layer 0
    gemm_mfma_kernel<<<GEMM_BLOCKS, 256, 0, stream>>>(x8, Wpack, dinv, t8, NN);
    agg_relu_kernel<<<AGG_BLOCKS, 256, 0, stream>>>(t8, offs, csrc, dinv, bc, h8);
    // layer 1
    gemm_mfma_kernel<<<GEMM_BLOCKS, 256, 0, stream>>>(h8, Wpack + 16384, dinv, t8, NN);
    agg_relu_kernel<<<AGG_BLOCKS, 256, 0, stream>>>(t8, offs, csrc, dinv, bc + HH, h8);
    // layer 2
    gemm_mfma_kernel<<<GEMM_BLOCKS, 256, 0, stream>>>(h8, Wpack + 2 * 16384, dinv, t8, NN);
    agg_relu_kernel<<<AGG_BLOCKS, 256, 0, stream>>>(t8, offs, csrc, dinv, bc + 2 * HH, h8);

    // fused pooling + readout
    pool_mlp_kernel<<<GG, 256, 0, stream>>>(h8, bat, Wl1, bl1, Wl2, bl2, out);
}

// Round 12
// 268.361 us; speedup vs baseline: 2.0408x; 1.0693x over previous
//
#include <hip/hip_runtime.h>
#include <hip/hip_bf16.h>
#include <hip/hip_fp8.h>

#define NN 100000
#define NE 1600000
#define FF 128
#define HH 128
#define CC 10
#define GG 64

#define NCHUNK 2048
#define CE 782            // ceil(NE/NCHUNK)
#define NBUCKET 128
#define BSPAN 782         // ceil(NN/NBUCKET)
#define XCONV_BLOCKS 6250 // NN*HH/8/256
#define PSEG 16

typedef __attribute__((ext_vector_type(8))) short short8;
typedef __attribute__((ext_vector_type(8))) unsigned short ushort8;
typedef __attribute__((ext_vector_type(4))) float f32x4;
typedef __attribute__((ext_vector_type(2))) float f32x2;

__device__ inline float bf2f(unsigned short u) {
    union { unsigned int i; float f; } x;
    x.i = ((unsigned int)u) << 16;
    return x.f;
}
__device__ inline unsigned short f2bf(float f) {
    union { float f; unsigned int i; } x;
    x.f = f;
    unsigned int r = x.i + 0x7FFF + ((x.i >> 16) & 1);  // RNE
    return (unsigned short)(r >> 16);
}
__device__ inline unsigned char f8enc(float v) {
    __hip_fp8_e4m3 q(v);
    return (unsigned char)q.__x;
}
__device__ inline float f8dec(unsigned char b) {
    __hip_fp8_e4m3 q;
    q.__x = (__hip_fp8_storage_t)b;
    return (float)q;
}

#if defined(__has_builtin)
#if __has_builtin(__builtin_amdgcn_cvt_pk_f32_fp8)
#define HAVE_CVT_PK_F32_FP8 1
#endif
#endif

// decode 8 fp8 (uint2) -> 8 f32
__device__ inline void dec8(uint2 v, float* o) {
#ifdef HAVE_CVT_PK_F32_FP8
    f32x2 p;
    p = __builtin_amdgcn_cvt_pk_f32_fp8(v.x, false); o[0] = p[0]; o[1] = p[1];
    p = __builtin_amdgcn_cvt_pk_f32_fp8(v.x, true);  o[2] = p[0]; o[3] = p[1];
    p = __builtin_amdgcn_cvt_pk_f32_fp8(v.y, false); o[4] = p[0]; o[5] = p[1];
    p = __builtin_amdgcn_cvt_pk_f32_fp8(v.y, true);  o[6] = p[0]; o[7] = p[1];
#else
#pragma unroll
    for (int j = 0; j < 4; ++j) {
        o[j]     = f8dec((v.x >> (8 * j)) & 0xFF);
        o[j + 4] = f8dec((v.y >> (8 * j)) & 0xFF);
    }
#endif
}
// encode 8 f32 -> uint2 of fp8
__device__ inline uint2 enc8(const float* d) {
    unsigned a = 0, b = 0;
#pragma unroll
    for (int j = 0; j < 4; ++j) {
        a |= ((unsigned)f8enc(d[j])) << (8 * j);
        b |= ((unsigned)f8enc(d[j + 4])) << (8 * j);
    }
    uint2 o; o.x = a; o.y = b; return o;
}

// -------- fused: x f32 -> fp8 convert (blocks < XCONV_BLOCKS) + weight combine/pack --------
__global__ __launch_bounds__(256) void combo_kernel(const float* __restrict__ x,
                                                    unsigned char* __restrict__ x8,
                                                    const float* __restrict__ W1, const float* __restrict__ b1,
                                                    const float* __restrict__ Wr1, const float* __restrict__ br1,
                                                    const float* __restrict__ W2, const float* __restrict__ b2,
                                                    const float* __restrict__ Wr, const float* __restrict__ br,
                                                    unsigned short* __restrict__ Wpack, float* __restrict__ bc) {
    int bid = blockIdx.x;
    if (bid < XCONV_BLOCKS) {
        int i = bid * 256 + threadIdx.x;      // 8-elem group
        float4 v0 = ((const float4*)x)[i * 2];
        float4 v1 = ((const float4*)x)[i * 2 + 1];
        float d[8] = {v0.x, v0.y, v0.z, v0.w, v1.x, v1.y, v1.z, v1.w};
        ((uint2*)x8)[i] = enc8(d);
        return;
    }
    int idx = (bid - XCONV_BLOCKS) * 256 + threadIdx.x;   // < 3*16384
    int l = idx / 16384, rem = idx % 16384;
    int cb = rem / 2048;
    int kb = (rem / 512) % 4;
    int lane = (rem / 8) % 64;
    int j = rem % 8;
    int k = kb * 32 + (lane >> 4) * 8 + j;
    int c = cb * 16 + (lane & 15);
    int wi = k * HH + c;
    float v = (l == 0) ? 0.95f * W1[wi] + 0.05f * Wr1[wi]
                       : 0.95f * W2[(l - 1) * 16384 + wi] + 0.05f * Wr[wi];
    Wpack[idx] = f2bf(v);
    if (rem < HH) {
        bc[l * HH + rem] = (l == 0) ? 0.95f * b1[rem] + 0.05f * br1[rem]
                                    : 0.95f * b2[(l - 1) * HH + rem] + 0.05f * br[rem];
    }
}

// ============ Phase A: deterministic edge partition by dst bucket ============
__global__ __launch_bounds__(256) void partA1_kernel(const int* __restrict__ ei,
                                                     int* __restrict__ cc) {
    __shared__ int h[NBUCKET];
    int c = blockIdx.x, t = threadIdx.x;
    if (t < NBUCKET) h[t] = 0;
    __syncthreads();
    int beg = c * CE, end = min(beg + CE, NE);
    for (int e = beg + t; e < end; e += 256) {
        int d = ei[NE + e];
        atomicAdd(&h[d / BSPAN], 1);
    }
    __syncthreads();
    if (t < NBUCKET) cc[c * NBUCKET + t] = h[t];
}

__global__ __launch_bounds__(256) void partA2_kernel(int* __restrict__ cc,
                                                     int* __restrict__ tot) {
    __shared__ int sh[256];
    int b = blockIdx.x, t = threadIdx.x;
    int v[8]; int s = 0;
#pragma unroll
    for (int i = 0; i < 8; ++i) { v[i] = cc[(t * 8 + i) * NBUCKET + b]; s += v[i]; }
    sh[t] = s; __syncthreads();
    for (int off = 1; off < 256; off <<= 1) {
        int x = (t >= off) ? sh[t - off] : 0; __syncthreads();
        sh[t] += x; __syncthreads();
    }
    int excl = sh[t] - s;
#pragma unroll
    for (int i = 0; i < 8; ++i) {
        cc[(t * 8 + i) * NBUCKET + b] = excl;
        excl += v[i];
    }
    if (t == 255) tot[b] = sh[255];
}

__global__ void scanB_kernel(const int* __restrict__ tot, int* __restrict__ bb) {
    if (threadIdx.x == 0 && blockIdx.x == 0) {
        int run = 0;
        for (int b = 0; b < NBUCKET; ++b) { bb[b] = run; run += tot[b]; }
        bb[NBUCKET] = run;
    }
}

// A3: scatter packed (dst,src) pairs into bucket-partitioned array via LDS cursors
__global__ __launch_bounds__(256) void partA3_kernel(const int* __restrict__ ei,
                                                     const int* __restrict__ cc,
                                                     const int* __restrict__ bb,
                                                     uint2* __restrict__ eb) {
    __shared__ int cur[NBUCKET];
    int c = blockIdx.x, t = threadIdx.x;
    if (t < NBUCKET) cur[t] = bb[t] + cc[c * NBUCKET + t];
    __syncthreads();
    int beg = c * CE, end = min(beg + CE, NE);
    for (int e = beg + t; e < end; e += 256) {
        int d = ei[NE + e];
        int s = ei[e];
        int p = atomicAdd(&cur[d / BSPAN], 1);
        uint2 pr; pr.x = (unsigned)d; pr.y = (unsigned)s;
        eb[p] = pr;
    }
}

__global__ __launch_bounds__(256) void partB1_kernel(const uint2* __restrict__ eb,
                                                     const int* __restrict__ bb,
                                                     int* __restrict__ cnt) {
    __shared__ int h[BSPAN];
    int b = blockIdx.x, t = threadIdx.x;
    int lo = b * BSPAN;
    int span = min(BSPAN, NN - lo);
    if (span <= 0) return;
    for (int i = t; i < span; i += 256) h[i] = 0;
    __syncthreads();
    int beg = bb[b], end = bb[b + 1];
    for (int e = beg + t; e < end; e += 256)
        atomicAdd(&h[eb[e].x - lo], 1);
    __syncthreads();
    for (int i = t; i < span; i += 256) cnt[lo + i] = h[i];
}

// ---------------- scan of cnt -> offs (+ dinv folded into scan3) ----------------
__global__ __launch_bounds__(256) void scan1_kernel(const int* __restrict__ cnt, int* __restrict__ bsum) {
    __shared__ int sh[256];
    int b = blockIdx.x, t = threadIdx.x;
    int base = b * 1024 + t * 4;
    int s = 0;
#pragma unroll
    for (int j = 0; j < 4; ++j) { int i = base + j; if (i < NN) s += cnt[i]; }
    sh[t] = s; __syncthreads();
    for (int off = 128; off; off >>= 1) { if (t < off) sh[t] += sh[t + off]; __syncthreads(); }
    if (t == 0) bsum[b] = sh[0];
}

__global__ void scan2_kernel(int* __restrict__ bsum, int nb) {
    if (threadIdx.x == 0 && blockIdx.x == 0) {
        int run = 0;
        for (int i = 0; i < nb; ++i) { int v = bsum[i]; bsum[i] = run; run += v; }
    }
}

__global__ __launch_bounds__(256) void scan3_kernel(const int* __restrict__ cnt, const int* __restrict__ bsum,
                                                    int* __restrict__ offs, float* __restrict__ dinv) {
    __shared__ int sh[256];
    int b = blockIdx.x, t = threadIdx.x;
    int base = b * 1024 + t * 4;
    int v[4]; int s = 0;
#pragma unroll
    for (int j = 0; j < 4; ++j) { int i = base + j; v[j] = (i < NN) ? cnt[i] : 0; s += v[j]; }
    sh[t] = s; __syncthreads();
    for (int off = 1; off < 256; off <<= 1) {
        int x = (t >= off) ? sh[t - off] : 0; __syncthreads();
        sh[t] += x; __syncthreads();
    }
    int excl = sh[t] - s + bsum[b];
#pragma unroll
    for (int j = 0; j < 4; ++j) {
        int i = base + j;
        if (i < NN) {
            offs[i] = excl; excl += v[j];
            dinv[i] = rsqrtf((float)v[j] + 1.0f);
        }
    }
    if (b == 0 && t == 0) offs[NN] = NE;
}

// B2: final CSR fill (src only) from bucketed edges; LDS cursors.
__global__ __launch_bounds__(256) void partB2_kernel(const uint2* __restrict__ eb,
                                                     const int* __restrict__ bb,
                                                     const int* __restrict__ offs,
                                                     int* __restrict__ csrc) {
    __shared__ int lcur[BSPAN];
    int b = blockIdx.x, t = threadIdx.x;
    int lo = b * BSPAN;
    int span = min(BSPAN, NN - lo);
    if (span <= 0) return;
    for (int i = t; i < span; i += 256) lcur[i] = offs[lo + i];
    __syncthreads();
    int beg = bb[b], end = bb[b + 1];
    for (int e = beg + t; e < end; e += 256) {
        uint2 pr = eb[e];
        int p = atomicAdd(&lcur[pr.x - lo], 1);
        csrc[p] = (int)pr.y;
    }
}

// ------- MFMA GEMM: t8[N,128](fp8) = rowscale(dinv) * (A8[N,128](fp8->bf16) @ Wc) -------
__global__ __launch_bounds__(256) void gemm_mfma_kernel(const unsigned char* __restrict__ A8,
                                                        const unsigned short* __restrict__ Wp,
                                                        const float* __restrict__ dinv,
                                                        unsigned char* __restrict__ out8,
                                                        int nrows) {
    __shared__ unsigned char f8s[64][128];
    int w = threadIdx.x >> 6;
    int l = threadIdx.x & 63;
    int m0 = blockIdx.x * 64 + w * 16;
    int kg = l >> 4;
    int cl = l & 15;
    int arow = m0 + cl;

    short8 a[4];
    if (arow < nrows) {
        const uint2* Ar = (const uint2*)(A8 + (size_t)arow * HH);
#pragma unroll
        for (int kb = 0; kb < 4; ++kb) {
            uint2 v = Ar[kb * 4 + kg];
            float d[8]; dec8(v, d);
            short8 t;
#pragma unroll
            for (int j = 0; j < 8; ++j) t[j] = (short)f2bf(d[j]);
            a[kb] = t;
        }
    } else {
        short8 z = {};
#pragma unroll
        for (int kb = 0; kb < 4; ++kb) a[kb] = z;
    }

    float dv[4];
#pragma unroll
    for (int r = 0; r < 4; ++r) {
        int orow = m0 + kg * 4 + r;
        dv[r] = (orow < nrows) ? dinv[orow] : 0.f;
    }

#pragma unroll
    for (int cb = 0; cb < 8; ++cb) {
        f32x4 acc = {0.f, 0.f, 0.f, 0.f};
#pragma unroll
        for (int kb = 0; kb < 4; ++kb) {
            short8 b = *(const short8*)(Wp + (size_t)(cb * 4 + kb) * 512 + l * 8);
            acc = __builtin_amdgcn_mfma_f32_16x16x32_bf16(a[kb], b, acc, 0, 0, 0);
        }
#pragma unroll
        for (int r = 0; r < 4; ++r)
            f8s[w * 16 + kg * 4 + r][cb * 16 + cl] = f8enc(acc[r] * dv[r]);
    }
    __syncthreads();
    int blk0 = blockIdx.x * 64;
    for (int u = threadIdx.x; u < 512; u += 256) {       // 64 rows x 8 x 16B
        int row = u >> 3, c16 = u & 7;
        int grow = blk0 + row;
        if (grow < nrows)
            ((uint4*)out8)[(size_t)grow * 8 + c16] = ((const uint4*)&f8s[row][0])[c16];
    }
}

// ---- aggregation: h8[n] = fp8(relu(dinv[n]*(t'[n] + sum_{s} t'[s]) + b)) ----
__global__ __launch_bounds__(256) void agg_relu_kernel(const unsigned char* __restrict__ t8,
                                                       const int* __restrict__ offs,
                                                       const int* __restrict__ csrc,
                                                       const float* __restrict__ dinv,
                                                       const float* __restrict__ bias,
                                                       unsigned char* __restrict__ hOut) {
    int n = blockIdx.x * 16 + (threadIdx.x >> 4);
    if (n >= NN) return;
    int lane = threadIdx.x & 15;          // features lane*8 .. lane*8+7
    int beg = offs[n], end = offs[n + 1];
    const uint2* g8 = (const uint2*)t8;
    float acc[8] = {};
    float d[8];
    int e = beg;
    for (; e + 3 < end; e += 4) {
        int s0 = csrc[e], s1 = csrc[e + 1], s2 = csrc[e + 2], s3 = csrc[e + 3];
        uint2 v0 = g8[(size_t)s0 * 16 + lane];
        uint2 v1 = g8[(size_t)s1 * 16 + lane];
        uint2 v2 = g8[(size_t)s2 * 16 + lane];
        uint2 v3 = g8[(size_t)s3 * 16 + lane];
        dec8(v0, d);
#pragma unroll
        for (int j = 0; j < 8; ++j) acc[j] += d[j];
        dec8(v1, d);
#pragma unroll
        for (int j = 0; j < 8; ++j) acc[j] += d[j];
        dec8(v2, d);
#pragma unroll
        for (int j = 0; j < 8; ++j) acc[j] += d[j];
        dec8(v3, d);
#pragma unroll
        for (int j = 0; j < 8; ++j) acc[j] += d[j];
    }
    for (; e < end; ++e) {
        uint2 v = g8[(size_t)csrc[e] * 16 + lane];
        dec8(v, d);
#pragma unroll
        for (int j = 0; j < 8; ++j) acc[j] += d[j];
    }
    {   // self term
        uint2 v = g8[(size_t)n * 16 + lane];
        dec8(v, d);
#pragma unroll
        for (int j = 0; j < 8; ++j) acc[j] += d[j];
    }
    float dn = dinv[n];
    float4 bv0 = ((const float4*)bias)[lane * 2];
    float4 bv1 = ((const float4*)bias)[lane * 2 + 1];
    float bb[8] = {bv0.x, bv0.y, bv0.z, bv0.w, bv1.x, bv1.y, bv1.z, bv1.w};
    float o[8];
#pragma unroll
    for (int j = 0; j < 8; ++j) o[j] = fmaxf(fmaf(acc[j], dn, bb[j]), 0.f);
    ((uint2*)hOut)[(size_t)n * 16 + lane] = enc8(o);
}

// -------- pooling stage 1: 16 segments/graph, partials to psum_seg (no atomics) --------
__global__ __launch_bounds__(256) void poolseg_kernel(const unsigned char* __restrict__ h8,
                                                      const int* __restrict__ batch,
                                                      float* __restrict__ psum_seg) {
    int g = blockIdx.x >> 4;
    int seg = blockIdx.x & (PSEG - 1);
    int t = threadIdx.x;
    int lo = 0, hi = NN;
    while (lo < hi) { int m = (lo + hi) >> 1; if (batch[m] < g) lo = m + 1; else hi = m; }
    int lb = lo;
    lo = 0; hi = NN;
    while (lo < hi) { int m = (lo + hi) >> 1; if (batch[m] <= g) lo = m + 1; else hi = m; }
    int ub = lo;
    int len = ub - lb;
    int b0 = lb + (int)(((long long)len * seg) / PSEG);
    int b1 = lb + (int)(((long long)len * (seg + 1)) / PSEG);

    int fg = t & 15;        // feature group: features fg*8 .. fg*8+7
    int rg = t >> 4;        // row slot 0..15
    const uint2* gp = (const uint2*)h8;
    float acc[8] = {};
    for (int n = b0 + rg; n < b1; n += 16) {
        uint2 v = gp[(size_t)n * 16 + fg];
        float d[8]; dec8(v, d);
#pragma unroll
        for (int j = 0; j < 8; ++j) acc[j] += d[j];
    }
    __shared__ float red[256][8];
#pragma unroll
    for (int j = 0; j < 8; ++j) red[t][j] = acc[j];
    __syncthreads();
    for (int off = 8; off >= 1; off >>= 1) {
        if (rg < off) {
#pragma unroll
            for (int j = 0; j < 8; ++j) red[t][j] += red[t + off * 16][j];
        }
        __syncthreads();
    }
    if (t < 16) {
#pragma unroll
        for (int j = 0; j < 8; ++j)
            psum_seg[((size_t)g * PSEG + seg) * HH + t * 8 + j] = red[t][j];
    }
}

// -------- pooling stage 2 + MLP + log_softmax: one block per graph --------
__global__ __launch_bounds__(128) void mlp2_kernel(const float* __restrict__ psum_seg,
                                                   const int* __restrict__ batch,
                                                   const float* __restrict__ Wl1,
                                                   const float* __restrict__ bl1,
                                                   const float* __restrict__ Wl2,
                                                   const float* __restrict__ bl2,
                                                   float* __restrict__ out) {
    __shared__ float p[128], o1[128], lg[CC];
    int g = blockIdx.x, t = threadIdx.x;
    int lo = 0, hi = NN;
    while (lo < hi) { int m = (lo + hi) >> 1; if (batch[m] < g) lo = m + 1; else hi = m; }
    int lb = lo;
    lo = 0; hi = NN;
    while (lo < hi) { int m = (lo + hi) >> 1; if (batch[m] <= g) lo = m + 1; else hi = m; }
    int len = lo - lb;
    float a = 0.f;
#pragma unroll
    for (int s = 0; s < PSEG; ++s)
        a += psum_seg[((size_t)g * PSEG + s) * HH + t];
    p[t] = a / fmaxf((float)len, 1.f);
    __syncthreads();
    float acc = bl1[t];
    for (int k = 0; k < HH; ++k) acc = fmaf(p[k], Wl1[k * HH + t], acc);
    o1[t] = fmaxf(acc, 0.f);
    __syncthreads();
    if (t < CC) {
        float a2 = bl2[t];
        for (int j = 0; j < HH; ++j) a2 = fmaf(o1[j], Wl2[j * CC + t], a2);
        lg[t] = a2;
    }
    __syncthreads();
    if (t == 0) {
        float m = lg[0];
        for (int c = 1; c < CC; ++c) m = fmaxf(m, lg[c]);
        float s = 0.f;
        for (int c = 0; c < CC; ++c) s += expf(lg[c] - m);
        float ls = logf(s);
        for (int c = 0; c < CC; ++c) out[g * CC + c] = lg[c] - m - ls;
    }
}

extern "C" void kernel_launch(void* const* d_in, const int* in_sizes, int n_in,
                              void* d_out, int out_size, void* d_ws, size_t ws_size,
                              hipStream_t stream) {
    const float* x   = (const float*)d_in[0];
    const int*   ei  = (const int*)d_in[1];
    const int*   bat = (const int*)d_in[2];
    const float* W1  = (const float*)d_in[3];
    const float* b1  = (const float*)d_in[4];
    const float* Wr1 = (const float*)d_in[5];
    const float* br1 = (const float*)d_in[6];
    const float* W2  = (const float*)d_in[7];
    const float* b2  = (const float*)d_in[8];
    const float* Wr  = (const float*)d_in[9];
    const float* br  = (const float*)d_in[10];
    const float* Wl1 = (const float*)d_in[11];
    const float* bl1 = (const float*)d_in[12];
    const float* Wl2 = (const float*)d_in[13];
    const float* bl2 = (const float*)d_in[14];
    float* out = (float*)d_out;

    // workspace carve-up (256B aligned)
    char* base = (char*)d_ws;
    size_t off = 0;
    auto alloc = [&](size_t bytes) {
        void* p = base + off;
        off += (bytes + 255) & ~(size_t)255;
        return p;
    };
    unsigned char* x8   = (unsigned char*)alloc((size_t)NN * HH);
    unsigned char* h8   = (unsigned char*)alloc((size_t)NN * HH);
    unsigned char* t8   = (unsigned char*)alloc((size_t)NN * HH);
    uint2* eb     = (uint2*)alloc((size_t)NE * 8);
    int*   cc     = (int*)alloc((size_t)NCHUNK * NBUCKET * 4);
    int*   csrc   = (int*)alloc((size_t)NE * 4);
    int*   offs   = (int*)alloc((size_t)(NN + 1) * 4);
    int*   cnt    = (int*)alloc((size_t)NN * 4);
    float* dinv   = (float*)alloc((size_t)NN * 4);
    int*   bsum   = (int*)alloc(128 * 4);
    unsigned short* Wpack = (unsigned short*)alloc(3 * 16384 * 2);
    float* bc     = (float*)alloc(3 * HH * 4);
    float* psum_seg = (float*)alloc((size_t)GG * PSEG * HH * 4);
    int*   tot    = (int*)alloc(NBUCKET * 4);
    int*   bb     = (int*)alloc((NBUCKET + 1) * 4);
    (void)ws_size; (void)in_sizes; (void)n_in; (void)out_size;

    // fused input-convert + weight combine
    combo_kernel<<<XCONV_BLOCKS + 192, 256, 0, stream>>>(x, x8, W1, b1, Wr1, br1,
                                                         W2, b2, Wr, br, Wpack, bc);

    // deterministic two-phase partition
    partA1_kernel<<<NCHUNK, 256, 0, stream>>>(ei, cc);
    partA2_kernel<<<NBUCKET, 256, 0, stream>>>(cc, tot);
    scanB_kernel<<<1, 64, 0, stream>>>(tot, bb);
    partA3_kernel<<<NCHUNK, 256, 0, stream>>>(ei, cc, bb, eb);
    partB1_kernel<<<NBUCKET, 256, 0, stream>>>(eb, bb, cnt);
    const int NB = (NN + 1023) / 1024;  // 98
    scan1_kernel<<<NB, 256, 0, stream>>>(cnt, bsum);
    scan2_kernel<<<1, 64, 0, stream>>>(bsum, NB);
    scan3_kernel<<<NB, 256, 0, stream>>>(cnt, bsum, offs, dinv);
    partB2_kernel<<<NBUCKET, 256, 0, stream>>>(eb, bb, offs, csrc);

    const int GEMM_BLOCKS = (NN + 63) / 64;
    const int AGG_BLOCKS = (NN + 15) / 16;
    // layer 0
    gemm_mfma_kernel<<<GEMM_BLOCKS, 256, 0, stream>>>(x8, Wpack, dinv, t8, NN);
    agg_relu_kernel<<<AGG_BLOCKS, 256, 0, stream>>>(t8, offs, csrc, dinv, bc, h8);
    // layer 1
    gemm_mfma_kernel<<<GEMM_BLOCKS, 256, 0, stream>>>(h8, Wpack + 16384, dinv, t8, NN);
    agg_relu_kernel<<<AGG_BLOCKS, 256, 0, stream>>>(t8, offs, csrc, dinv, bc + HH, h8);
    // layer 2
    gemm_mfma_kernel<<<GEMM_BLOCKS, 256, 0, stream>>>(h8, Wpack + 2 * 16384, dinv, t8, NN);
    agg_relu_kernel<<<AGG_BLOCKS, 256, 0, stream>>>(t8, offs, csrc, dinv, bc + 2 * HH, h8);

    // pooling (parallel segments, no atomics) + readout
    poolseg_kernel<<<GG * PSEG, 256, 0, stream>>>(h8, bat, psum_seg);
    mlp2_kernel<<<GG, 128, 0, stream>>>(psum_seg, bat, Wl1, bl1, Wl2, bl2, out);
}